// Round 1
// baseline (2435.362 us; speedup 1.0000x reference)
//
#include <hip/hip_runtime.h>
#include <math.h>

// ---------------- CSR build ----------------

__global__ __launch_bounds__(256) void k_init_deg(int* deg, int n) {
    int i = blockIdx.x * 256 + threadIdx.x;
    if (i < n) deg[i] = 1;  // self-loop
}

__global__ __launch_bounds__(256) void k_count(const int* __restrict__ col, int* deg, int E) {
    int e = blockIdx.x * 256 + threadIdx.x;
    if (e < E) atomicAdd(&deg[col[e]], 1);
}

__global__ __launch_bounds__(256) void k_dis(const int* __restrict__ deg, float* __restrict__ dis, int n) {
    int i = blockIdx.x * 256 + threadIdx.x;
    if (i < n) dis[i] = 1.0f / sqrtf((float)deg[i]);
}

// exclusive scan of (deg[i]-1) -> offs[0..n], also copy to cursor
__global__ __launch_bounds__(1024) void k_scan(const int* __restrict__ deg,
                                               int* __restrict__ offs, int* __restrict__ cursor, int n) {
    __shared__ int tmp[1024];
    __shared__ int carry_s;
    if (threadIdx.x == 0) carry_s = 0;
    __syncthreads();
    for (int base = 0; base < n; base += 1024) {
        int i = base + threadIdx.x;
        int v = (i < n) ? (deg[i] - 1) : 0;
        tmp[threadIdx.x] = v;
        __syncthreads();
        for (int off = 1; off < 1024; off <<= 1) {
            int t = (threadIdx.x >= off) ? tmp[threadIdx.x - off] : 0;
            __syncthreads();
            tmp[threadIdx.x] += t;
            __syncthreads();
        }
        int incl = tmp[threadIdx.x];
        int carry = carry_s;
        if (i < n) { int ex = carry + incl - v; offs[i] = ex; cursor[i] = ex; }
        __syncthreads();
        if (threadIdx.x == 1023) carry_s += tmp[1023];
        __syncthreads();
    }
    if (threadIdx.x == 0) offs[n] = carry_s;
}

__global__ __launch_bounds__(256) void k_fill(const int* __restrict__ row, const int* __restrict__ col,
                                              const float* __restrict__ dis, int* cursor,
                                              int* __restrict__ csr_row, float* __restrict__ csr_val, int E) {
    int e = blockIdx.x * 256 + threadIdx.x;
    if (e >= E) return;
    int c = col[e];
    int r = row[e];
    int pos = atomicAdd(&cursor[c], 1);
    csr_row[pos] = r;
    csr_val[pos] = dis[r];
}

// ---------------- GEMM: H = (BN? X*scale+shift : X) @ W ----------------
// tile 64 rows x COUT cols, block 256 threads (16x16 thread grid, 4 rows x COUT/16 cols each)

template <int K, int COUT, bool BN>
__global__ __launch_bounds__(256) void k_gemm(const float* __restrict__ X, const float* __restrict__ W,
                                              const float* __restrict__ ss, float* __restrict__ H, int n) {
    __shared__ float Xs[64][K + 1];   // +1 pad breaks bank conflicts on row-strided reads
    __shared__ float Ws[K][COUT];
    const int rb = blockIdx.x * 64;
    const float4* Wv = (const float4*)W;
    float4* Wsv = (float4*)&Ws[0][0];
    for (int i = threadIdx.x; i < K * COUT / 4; i += 256) Wsv[i] = Wv[i];
    const float4* Xv = (const float4*)X;
    for (int i = threadIdx.x; i < 64 * (K / 4); i += 256) {
        int r = i / (K / 4), kq = i - r * (K / 4);
        int gr = rb + r;
        float4 v;
        if (gr < n) v = Xv[(size_t)gr * (K / 4) + kq];
        else { v.x = v.y = v.z = v.w = 0.f; }
        int k0 = kq * 4;
        if (BN) {
            v.x = v.x * ss[k0]     + ss[K + k0];
            v.y = v.y * ss[k0 + 1] + ss[K + k0 + 1];
            v.z = v.z * ss[k0 + 2] + ss[K + k0 + 2];
            v.w = v.w * ss[k0 + 3] + ss[K + k0 + 3];
        }
        Xs[r][k0] = v.x; Xs[r][k0 + 1] = v.y; Xs[r][k0 + 2] = v.z; Xs[r][k0 + 3] = v.w;
    }
    __syncthreads();
    const int tx = threadIdx.x & 15;
    const int ty = threadIdx.x >> 4;
    constexpr int CPT = COUT / 16;
    float acc[4][CPT];
#pragma unroll
    for (int r = 0; r < 4; r++)
#pragma unroll
        for (int c = 0; c < CPT; c++) acc[r][c] = 0.f;

#pragma unroll 2
    for (int k = 0; k < K; ++k) {
        float xv[4];
#pragma unroll
        for (int r = 0; r < 4; r++) xv[r] = Xs[ty * 4 + r][k];
#pragma unroll
        for (int c = 0; c < CPT; c++) {
            float wv = Ws[k][c * 16 + tx];
#pragma unroll
            for (int r = 0; r < 4; r++) acc[r][c] += xv[r] * wv;
        }
    }
#pragma unroll
    for (int r = 0; r < 4; r++) {
        int gr = rb + ty * 4 + r;
        if (gr < n) {
#pragma unroll
            for (int c = 0; c < CPT; c++) H[(size_t)gr * COUT + c * 16 + tx] = acc[r][c];
        }
    }
}

// ---------------- aggregation + bias + ReLU + BN partial stats ----------------
// one wave per node (grid-stride); lane covers C/64 contiguous channels

template <int C>
__global__ __launch_bounds__(256) void k_agg(const float* __restrict__ H, const int* __restrict__ offs,
                                             const int* __restrict__ csr_row, const float* __restrict__ csr_val,
                                             const float* __restrict__ dis, const float* __restrict__ bias,
                                             float* __restrict__ Y, float* __restrict__ part, int n) {
    constexpr int VPL = C / 64;   // 1 or 2 channels per lane
    const int lane = threadIdx.x & 63;
    const int wave = threadIdx.x >> 6;
    const int gw = blockIdx.x * 4 + wave;
    const int nw = gridDim.x * 4;
    float bsum[VPL], bsq[VPL], bias_r[VPL];
#pragma unroll
    for (int q = 0; q < VPL; q++) { bsum[q] = 0.f; bsq[q] = 0.f; bias_r[q] = bias[lane * VPL + q]; }

    for (int node = gw; node < n; node += nw) {
        int s0 = offs[node], s1 = offs[node + 1];
        float a[VPL];
#pragma unroll
        for (int q = 0; q < VPL; q++) a[q] = 0.f;
        for (int e = s0; e < s1; ++e) {
            int r = csr_row[e];
            float v = csr_val[e];
            const float* hp = H + (size_t)r * C + lane * VPL;
            if (VPL == 2) {
                float2 h2 = *(const float2*)hp;
                a[0] += v * h2.x; a[1] += v * h2.y;
            } else {
                a[0] += v * hp[0];
            }
        }
        float dn = dis[node];
        const float* hs = H + (size_t)node * C + lane * VPL;
        float outv[VPL];
#pragma unroll
        for (int q = 0; q < VPL; q++) {
            float val = a[q] * dn + hs[q] * dn * dn + bias_r[q];
            val = fmaxf(val, 0.f);
            outv[q] = val;
            bsum[q] += val;
            bsq[q] += val * val;
        }
        float* yp = Y + (size_t)node * C + lane * VPL;
        if (VPL == 2) *(float2*)yp = make_float2(outv[0], outv[1]);
        else yp[0] = outv[0];
    }
    __shared__ float psum[4][C], psq[4][C];
#pragma unroll
    for (int q = 0; q < VPL; q++) { psum[wave][lane * VPL + q] = bsum[q]; psq[wave][lane * VPL + q] = bsq[q]; }
    __syncthreads();
    for (int c = threadIdx.x; c < C; c += 256) {
        float s = psum[0][c] + psum[1][c] + psum[2][c] + psum[3][c];
        float qq = psq[0][c] + psq[1][c] + psq[2][c] + psq[3][c];
        part[(size_t)blockIdx.x * 2 * C + c] = s;
        part[(size_t)blockIdx.x * 2 * C + C + c] = qq;
    }
}

// ---------------- BN finalize: reduce block partials -> scale/shift ----------------

template <int C>
__global__ void k_bnfin(const float* __restrict__ part, int nblk, const float* __restrict__ g,
                        const float* __restrict__ bt, float* __restrict__ ss, int n) {
    int c = threadIdx.x;
    if (c >= C) return;
    double s = 0.0, q = 0.0;
#pragma unroll 4
    for (int b = 0; b < nblk; b++) {
        s += (double)part[(size_t)b * 2 * C + c];
        q += (double)part[(size_t)b * 2 * C + C + c];
    }
    double invN = 1.0 / (double)n;
    double mu = s * invN;
    double var = q * invN - mu * mu;
    float scale = g[c] / sqrtf((float)var + 1e-5f);
    ss[c] = scale;
    ss[C + c] = bt[c] - (float)mu * scale;
}

// ---------------- edge-pair scoring MLP ----------------
// block 256 (4 waves), fcW1 (128KB) staged in LDS, 4 pairs per wave,
// emb tile transposed so inner loop does one float4 broadcast per k.

__global__ __launch_bounds__(256) void k_score(const float* __restrict__ Y3, const float* __restrict__ ss,
                                               const int* __restrict__ src, const int* __restrict__ dst,
                                               const float* __restrict__ fcW1, const float* __restrict__ fcb1,
                                               const float* __restrict__ fcW2, const float* __restrict__ fcb2,
                                               float* __restrict__ out, int P) {
    __shared__ float W1s[256 * 128];
    __shared__ float W2s[128];
    __shared__ float embs[4][256][4];
    for (int i = threadIdx.x; i < 256 * 128 / 4; i += 256)
        ((float4*)W1s)[i] = ((const float4*)fcW1)[i];
    if (threadIdx.x < 128) W2s[threadIdx.x] = fcW2[threadIdx.x];
    __syncthreads();
    const int lane = threadIdx.x & 63;
    const int wave = threadIdx.x >> 6;
    const float sc0 = ss[lane], sc1 = ss[64 + lane];
    const float sh0 = ss[128 + lane], sh1 = ss[192 + lane];
    const float b1v0 = fcb1[lane], b1v1 = fcb1[64 + lane];
    const float w2v0 = W2s[lane], w2v1 = W2s[64 + lane];
    const float b2v = fcb2[0];
    const int ngroups = (P + 15) >> 4;
    for (int g = blockIdx.x; g < ngroups; g += gridDim.x) {
        const int pbase = g * 16 + wave * 4;
#pragma unroll
        for (int p = 0; p < 4; ++p) {
            int pi = pbase + p;
            int is = 0, id = 0;
            if (pi < P) { is = src[pi]; id = dst[pi]; }
            float v0 = Y3[(size_t)is * 128 + lane] * sc0 + sh0;
            float v1 = Y3[(size_t)is * 128 + 64 + lane] * sc1 + sh1;
            float v2 = Y3[(size_t)id * 128 + lane] * sc0 + sh0;
            float v3 = Y3[(size_t)id * 128 + 64 + lane] * sc1 + sh1;
            embs[wave][lane][p] = v0;
            embs[wave][64 + lane][p] = v1;
            embs[wave][128 + lane][p] = v2;
            embs[wave][192 + lane][p] = v3;
        }
        float accA[4] = {0.f, 0.f, 0.f, 0.f};
        float accB[4] = {0.f, 0.f, 0.f, 0.f};
#pragma unroll 4
        for (int k = 0; k < 256; ++k) {
            float4 e = *(const float4*)&embs[wave][k][0];
            float w0 = W1s[k * 128 + lane];
            float w1 = W1s[k * 128 + 64 + lane];
            accA[0] += e.x * w0; accB[0] += e.x * w1;
            accA[1] += e.y * w0; accB[1] += e.y * w1;
            accA[2] += e.z * w0; accB[2] += e.z * w1;
            accA[3] += e.w * w0; accB[3] += e.w * w1;
        }
#pragma unroll
        for (int p = 0; p < 4; ++p) {
            float h0 = fmaxf(accA[p] + b1v0, 0.f);
            float h1 = fmaxf(accB[p] + b1v1, 0.f);
            float s = h0 * w2v0 + h1 * w2v1;
#pragma unroll
            for (int off = 32; off; off >>= 1) s += __shfl_xor(s, off);
            int pi = pbase + p;
            if (lane == 0 && pi < P) out[pi] = s + b2v;
        }
    }
}

// ---------------- launch ----------------

extern "C" void kernel_launch(void* const* d_in, const int* in_sizes, int n_in,
                              void* d_out, int out_size, void* d_ws, size_t ws_size,
                              hipStream_t stream) {
    const float* x   = (const float*)d_in[0];
    const int* ei    = (const int*)d_in[1];
    const int* src   = (const int*)d_in[2];
    const int* dst   = (const int*)d_in[3];
    const float* W1  = (const float*)d_in[4];
    const float* b1  = (const float*)d_in[5];
    const float* W2  = (const float*)d_in[6];
    const float* b2  = (const float*)d_in[7];
    const float* W3  = (const float*)d_in[8];
    const float* b3  = (const float*)d_in[9];
    const float* g1  = (const float*)d_in[10];
    const float* bt1 = (const float*)d_in[11];
    const float* g2  = (const float*)d_in[12];
    const float* bt2 = (const float*)d_in[13];
    const float* g3  = (const float*)d_in[14];
    const float* bt3 = (const float*)d_in[15];
    const float* fcW1 = (const float*)d_in[16];
    const float* fcb1 = (const float*)d_in[17];
    const float* fcW2 = (const float*)d_in[18];
    const float* fcb2 = (const float*)d_in[19];
    float* out = (float*)d_out;

    const int N = in_sizes[0] / 128;   // 50000
    const int E = in_sizes[1] / 2;     // 1600000
    const int P = in_sizes[2];         // 200000
    const int* erow = ei;
    const int* ecol = ei + E;

    // workspace carve (256B aligned)
    char* w = (char*)d_ws;
    auto alloc = [&](size_t bytes) { void* p = (void*)w; w += (bytes + 255) & ~(size_t)255; return p; };
    int*   deg     = (int*)alloc((size_t)N * 4);
    float* dis     = (float*)alloc((size_t)N * 4);
    int*   offs    = (int*)alloc((size_t)(N + 1) * 4);
    int*   cursor  = (int*)alloc((size_t)N * 4);
    int*   csr_row = (int*)alloc((size_t)E * 4);
    float* csr_val = (float*)alloc((size_t)E * 4);
    float* part    = (float*)alloc((size_t)512 * 256 * 4);
    float* ss1     = (float*)alloc(2 * 64 * 4);
    float* ss2     = (float*)alloc(2 * 128 * 4);
    float* ss3     = (float*)alloc(2 * 128 * 4);
    float* bufA    = (float*)alloc((size_t)N * 128 * 4);
    float* bufB    = (float*)alloc((size_t)N * 128 * 4);
    (void)ws_size; (void)n_in; (void)out_size;

    const int nb_n = (N + 255) / 256;
    const int nb_e = (E + 255) / 256;

    // CSR build (reused by all 3 layers)
    k_init_deg<<<nb_n, 256, 0, stream>>>(deg, N);
    k_count<<<nb_e, 256, 0, stream>>>(ecol, deg, E);
    k_dis<<<nb_n, 256, 0, stream>>>(deg, dis, N);
    k_scan<<<1, 1024, 0, stream>>>(deg, offs, cursor, N);
    k_fill<<<nb_e, 256, 0, stream>>>(erow, ecol, dis, cursor, csr_row, csr_val, E);

    const int gemm_grid = (N + 63) / 64;

    // layer 1: x[N,128] @ W1[128,64] -> agg -> relu -> BN stats
    k_gemm<128, 64, false><<<gemm_grid, 256, 0, stream>>>(x, W1, nullptr, bufA, N);
    k_agg<64><<<512, 256, 0, stream>>>(bufA, offs, csr_row, csr_val, dis, b1, bufB, part, N);
    k_bnfin<64><<<1, 64, 0, stream>>>(part, 512, g1, bt1, ss1, N);

    // layer 2: z1[N,64] @ W2[64,128]
    k_gemm<64, 128, true><<<gemm_grid, 256, 0, stream>>>(bufB, W2, ss1, bufA, N);
    k_agg<128><<<512, 256, 0, stream>>>(bufA, offs, csr_row, csr_val, dis, b2, bufB, part, N);
    k_bnfin<128><<<1, 128, 0, stream>>>(part, 512, g2, bt2, ss2, N);

    // layer 3: z2[N,128] @ W3[128,128]
    k_gemm<128, 128, true><<<gemm_grid, 256, 0, stream>>>(bufB, W3, ss2, bufA, N);
    k_agg<128><<<512, 256, 0, stream>>>(bufA, offs, csr_row, csr_val, dis, b3, bufB, part, N);
    k_bnfin<128><<<1, 128, 0, stream>>>(part, 512, g3, bt3, ss3, N);

    // edge-pair scoring
    k_score<<<256, 256, 0, stream>>>(bufB, ss3, src, dst, fcW1, fcb1, fcW2, fcb2, out, P);
}

// Round 2
// 1278.754 us; speedup vs baseline: 1.9045x; 1.9045x over previous
//
#include <hip/hip_runtime.h>
#include <math.h>

// ---------------- CSR build ----------------

__global__ __launch_bounds__(256) void k_init_deg(int* deg, int n) {
    int i = blockIdx.x * 256 + threadIdx.x;
    if (i < n) deg[i] = 1;  // self-loop
}

__global__ __launch_bounds__(256) void k_count(const int* __restrict__ col, int* deg, int E) {
    int e = blockIdx.x * 256 + threadIdx.x;
    if (e < E) atomicAdd(&deg[col[e]], 1);
}

__global__ __launch_bounds__(256) void k_dis(const int* __restrict__ deg, float* __restrict__ dis, int n) {
    int i = blockIdx.x * 256 + threadIdx.x;
    if (i < n) dis[i] = 1.0f / sqrtf((float)deg[i]);
}

// hierarchical exclusive scan of (deg[i]-1) -> offs[0..n] + cursor copy
__global__ __launch_bounds__(1024) void k_scan_blk(const int* __restrict__ deg,
                                                   int* __restrict__ offs, int* __restrict__ bsum, int n) {
    __shared__ int tmp[1024];
    int i = blockIdx.x * 1024 + threadIdx.x;
    int v = (i < n) ? (deg[i] - 1) : 0;
    tmp[threadIdx.x] = v;
    __syncthreads();
    for (int off = 1; off < 1024; off <<= 1) {
        int t = (threadIdx.x >= off) ? tmp[threadIdx.x - off] : 0;
        __syncthreads();
        tmp[threadIdx.x] += t;
        __syncthreads();
    }
    if (i < n) offs[i] = tmp[threadIdx.x] - v;   // block-local exclusive
    if (threadIdx.x == 1023) bsum[blockIdx.x] = tmp[1023];
}

__global__ void k_scan_top(int* bsum, int nb) {
    if (threadIdx.x == 0) {
        int acc = 0;
        for (int b = 0; b < nb; b++) { int t = bsum[b]; bsum[b] = acc; acc += t; }
        bsum[nb] = acc;
    }
}

__global__ __launch_bounds__(1024) void k_scan_add(int* __restrict__ offs, int* __restrict__ cursor,
                                                   const int* __restrict__ bsum, int n, int nb) {
    int i = blockIdx.x * 1024 + threadIdx.x;
    if (i < n) {
        int v = offs[i] + bsum[blockIdx.x];
        offs[i] = v;
        cursor[i] = v;
    }
    if (i == 0) offs[n] = bsum[nb];
}

__global__ __launch_bounds__(256) void k_fill(const int* __restrict__ row, const int* __restrict__ col,
                                              const float* __restrict__ dis, int* cursor,
                                              int* __restrict__ csr_row, float* __restrict__ csr_val, int E) {
    int e = blockIdx.x * 256 + threadIdx.x;
    if (e >= E) return;
    int c = col[e];
    int r = row[e];
    int pos = atomicAdd(&cursor[c], 1);
    csr_row[pos] = r;
    csr_val[pos] = dis[r];
}

// ---------------- GEMM: H = (BN? X*scale+shift : X) @ W ----------------
// tile 64 rows x COUT cols, K chunked at 64 to keep LDS <= ~48KB -> >=3 blocks/CU

template <int K, int COUT, bool BN>
__global__ __launch_bounds__(256) void k_gemm(const float* __restrict__ X, const float* __restrict__ W,
                                              const float* __restrict__ ss, float* __restrict__ H, int n) {
    __shared__ float Xs[64][64 + 1];
    __shared__ float Ws[64][COUT];
    const int rb = blockIdx.x * 64;
    const int tx = threadIdx.x & 15;
    const int ty = threadIdx.x >> 4;
    constexpr int CPT = COUT / 16;
    float acc[4][CPT];
#pragma unroll
    for (int r = 0; r < 4; r++)
#pragma unroll
        for (int c = 0; c < CPT; c++) acc[r][c] = 0.f;

    for (int kc = 0; kc < K; kc += 64) {
        // stage W chunk: rows kc..kc+63
        {
            const float4* Wv = (const float4*)(W + (size_t)kc * COUT);
            float4* Wsv = (float4*)&Ws[0][0];
            for (int i = threadIdx.x; i < 64 * COUT / 4; i += 256) Wsv[i] = Wv[i];
        }
        // stage X chunk with optional BN fold
        {
            const float4* Xv = (const float4*)X;
            for (int i = threadIdx.x; i < 64 * 16; i += 256) {
                int r = i >> 4, kq = i & 15;
                int gr = rb + r;
                float4 v;
                if (gr < n) v = Xv[(size_t)gr * (K / 4) + (kc / 4) + kq];
                else { v.x = v.y = v.z = v.w = 0.f; }
                int k0 = kc + kq * 4;
                if (BN) {
                    v.x = v.x * ss[k0]     + ss[K + k0];
                    v.y = v.y * ss[k0 + 1] + ss[K + k0 + 1];
                    v.z = v.z * ss[k0 + 2] + ss[K + k0 + 2];
                    v.w = v.w * ss[k0 + 3] + ss[K + k0 + 3];
                }
                int kl = kq * 4;
                Xs[r][kl] = v.x; Xs[r][kl + 1] = v.y; Xs[r][kl + 2] = v.z; Xs[r][kl + 3] = v.w;
            }
        }
        __syncthreads();
#pragma unroll 2
        for (int k = 0; k < 64; ++k) {
            float xv[4];
#pragma unroll
            for (int r = 0; r < 4; r++) xv[r] = Xs[ty * 4 + r][k];
#pragma unroll
            for (int c = 0; c < CPT; c++) {
                float wv = Ws[k][c * 16 + tx];
#pragma unroll
                for (int r = 0; r < 4; r++) acc[r][c] += xv[r] * wv;
            }
        }
        __syncthreads();
    }
#pragma unroll
    for (int r = 0; r < 4; r++) {
        int gr = rb + ty * 4 + r;
        if (gr < n) {
#pragma unroll
            for (int c = 0; c < CPT; c++) H[(size_t)gr * COUT + c * 16 + tx] = acc[r][c];
        }
    }
}

// ---------------- aggregation + bias + ReLU + BN partial stats ----------------
// one wave per node (grid-stride); lane covers C/64 contiguous channels

template <int C>
__global__ __launch_bounds__(256) void k_agg(const float* __restrict__ H, const int* __restrict__ offs,
                                             const int* __restrict__ csr_row, const float* __restrict__ csr_val,
                                             const float* __restrict__ dis, const float* __restrict__ bias,
                                             float* __restrict__ Y, float* __restrict__ part, int n) {
    constexpr int VPL = C / 64;   // 1 or 2 channels per lane
    const int lane = threadIdx.x & 63;
    const int wave = threadIdx.x >> 6;
    const int gw = blockIdx.x * 4 + wave;
    const int nw = gridDim.x * 4;
    float bsum[VPL], bsq[VPL], bias_r[VPL];
#pragma unroll
    for (int q = 0; q < VPL; q++) { bsum[q] = 0.f; bsq[q] = 0.f; bias_r[q] = bias[lane * VPL + q]; }

    for (int node = gw; node < n; node += nw) {
        int s0 = offs[node], s1 = offs[node + 1];
        float a[VPL];
#pragma unroll
        for (int q = 0; q < VPL; q++) a[q] = 0.f;
        for (int e = s0; e < s1; ++e) {
            int r = csr_row[e];
            float v = csr_val[e];
            const float* hp = H + (size_t)r * C + lane * VPL;
            if (VPL == 2) {
                float2 h2 = *(const float2*)hp;
                a[0] += v * h2.x; a[1] += v * h2.y;
            } else {
                a[0] += v * hp[0];
            }
        }
        float dn = dis[node];
        const float* hs = H + (size_t)node * C + lane * VPL;
        float outv[VPL];
#pragma unroll
        for (int q = 0; q < VPL; q++) {
            float val = a[q] * dn + hs[q] * dn * dn + bias_r[q];
            val = fmaxf(val, 0.f);
            outv[q] = val;
            bsum[q] += val;
            bsq[q] += val * val;
        }
        float* yp = Y + (size_t)node * C + lane * VPL;
        if (VPL == 2) *(float2*)yp = make_float2(outv[0], outv[1]);
        else yp[0] = outv[0];
    }
    __shared__ float psum[4][C], psq[4][C];
#pragma unroll
    for (int q = 0; q < VPL; q++) { psum[wave][lane * VPL + q] = bsum[q]; psq[wave][lane * VPL + q] = bsq[q]; }
    __syncthreads();
    for (int c = threadIdx.x; c < C; c += 256) {
        float s = psum[0][c] + psum[1][c] + psum[2][c] + psum[3][c];
        float qq = psq[0][c] + psq[1][c] + psq[2][c] + psq[3][c];
        part[(size_t)blockIdx.x * 2 * C + c] = s;
        part[(size_t)blockIdx.x * 2 * C + C + c] = qq;
    }
}

// ---------------- BN finalize: reduce block partials -> scale/shift ----------------

template <int C>
__global__ __launch_bounds__(1024) void k_bnfin(const float* __restrict__ part, int nblk,
                                                const float* __restrict__ g, const float* __restrict__ bt,
                                                float* __restrict__ ss, int n) {
    constexpr int ROWS = 1024 / C;
    __shared__ float ssum[1024], ssq[1024];
    const int c = threadIdx.x % C;
    const int r = threadIdx.x / C;
    float s = 0.f, q = 0.f;
    for (int b = r; b < nblk; b += ROWS) {
        s += part[(size_t)b * 2 * C + c];
        q += part[(size_t)b * 2 * C + C + c];
    }
    ssum[threadIdx.x] = s; ssq[threadIdx.x] = q;
    __syncthreads();
    if (r == 0) {
        double S = (double)s, Q = (double)q;
        for (int rr = 1; rr < ROWS; rr++) { S += (double)ssum[rr * C + c]; Q += (double)ssq[rr * C + c]; }
        double invN = 1.0 / (double)n;
        double mu = S * invN;
        double var = Q * invN - mu * mu;
        float scale = g[c] / sqrtf((float)var + 1e-5f);
        ss[c] = scale;
        ss[C + c] = bt[c] - (float)mu * scale;
    }
}

// ---------------- edge-pair scoring MLP ----------------
// 4 waves/block, 8 pairs/wave. W1 read from global (L2-hot, 128KB, reread by all).
// emb tile per-wave in LDS (8KB) -> 32KB/block -> ~5 blocks/CU.
// No __syncthreads needed: each wave's LDS region is private (wave-lockstep).

__global__ __launch_bounds__(256) void k_score(const float* __restrict__ Y3, const float* __restrict__ ss,
                                               const int* __restrict__ src, const int* __restrict__ dst,
                                               const float* __restrict__ fcW1, const float* __restrict__ fcb1,
                                               const float* __restrict__ fcW2, const float* __restrict__ fcb2,
                                               float* __restrict__ out, int P) {
    __shared__ float embs[4][256][8];
    const int lane = threadIdx.x & 63;
    const int wave = threadIdx.x >> 6;
    const int c0 = 2 * lane;
    const float2 b1v = *(const float2*)&fcb1[c0];
    const float2 w2v = *(const float2*)&fcW2[c0];
    const float b2v = fcb2[0];
    const float sc0 = ss[lane], sc1 = ss[64 + lane];
    const float sh0 = ss[128 + lane], sh1 = ss[192 + lane];
    const int pbase = (blockIdx.x * 4 + wave) * 8;
    float (*E)[8] = embs[wave];

    // gather + BN fold, transposed into LDS
#pragma unroll
    for (int p = 0; p < 8; ++p) {
        int pi = pbase + p;
        if (pi < P) {
            int is = src[pi], id = dst[pi];
            float v0 = Y3[(size_t)is * 128 + lane] * sc0 + sh0;
            float v1 = Y3[(size_t)is * 128 + 64 + lane] * sc1 + sh1;
            float v2 = Y3[(size_t)id * 128 + lane] * sc0 + sh0;
            float v3 = Y3[(size_t)id * 128 + 64 + lane] * sc1 + sh1;
            E[lane][p] = v0;
            E[64 + lane][p] = v1;
            E[128 + lane][p] = v2;
            E[192 + lane][p] = v3;
        }
    }

    float acc[8][2];
#pragma unroll
    for (int p = 0; p < 8; p++) { acc[p][0] = 0.f; acc[p][1] = 0.f; }

    const float2* W1v = (const float2*)fcW1 + lane;   // element (k, 2*lane)
#pragma unroll 4
    for (int k = 0; k < 256; ++k) {
        float2 w = W1v[(size_t)k * 64];
        float4 ea = *(const float4*)&E[k][0];
        float4 eb = *(const float4*)&E[k][4];
        float ev[8] = {ea.x, ea.y, ea.z, ea.w, eb.x, eb.y, eb.z, eb.w};
#pragma unroll
        for (int p = 0; p < 8; p++) {
            acc[p][0] += ev[p] * w.x;
            acc[p][1] += ev[p] * w.y;
        }
    }

#pragma unroll
    for (int p = 0; p < 8; ++p) {
        float h0 = fmaxf(acc[p][0] + b1v.x, 0.f);
        float h1 = fmaxf(acc[p][1] + b1v.y, 0.f);
        float s = h0 * w2v.x + h1 * w2v.y;
#pragma unroll
        for (int off = 32; off; off >>= 1) s += __shfl_xor(s, off);
        int pi = pbase + p;
        if (lane == 0 && pi < P) out[pi] = s + b2v;
    }
}

// ---------------- launch ----------------

extern "C" void kernel_launch(void* const* d_in, const int* in_sizes, int n_in,
                              void* d_out, int out_size, void* d_ws, size_t ws_size,
                              hipStream_t stream) {
    const float* x   = (const float*)d_in[0];
    const int* ei    = (const int*)d_in[1];
    const int* src   = (const int*)d_in[2];
    const int* dst   = (const int*)d_in[3];
    const float* W1  = (const float*)d_in[4];
    const float* b1  = (const float*)d_in[5];
    const float* W2  = (const float*)d_in[6];
    const float* b2  = (const float*)d_in[7];
    const float* W3  = (const float*)d_in[8];
    const float* b3  = (const float*)d_in[9];
    const float* g1  = (const float*)d_in[10];
    const float* bt1 = (const float*)d_in[11];
    const float* g2  = (const float*)d_in[12];
    const float* bt2 = (const float*)d_in[13];
    const float* g3  = (const float*)d_in[14];
    const float* bt3 = (const float*)d_in[15];
    const float* fcW1 = (const float*)d_in[16];
    const float* fcb1 = (const float*)d_in[17];
    const float* fcW2 = (const float*)d_in[18];
    const float* fcb2 = (const float*)d_in[19];
    float* out = (float*)d_out;

    const int N = in_sizes[0] / 128;   // 50000
    const int E = in_sizes[1] / 2;     // 1600000
    const int P = in_sizes[2];         // 200000
    const int* erow = ei;
    const int* ecol = ei + E;

    const int AGG_GRID = 2048;

    // workspace carve (256B aligned)
    char* w = (char*)d_ws;
    auto alloc = [&](size_t bytes) { void* p = (void*)w; w += (bytes + 255) & ~(size_t)255; return p; };
    int*   deg     = (int*)alloc((size_t)N * 4);
    float* dis     = (float*)alloc((size_t)N * 4);
    int*   offs    = (int*)alloc((size_t)(N + 1) * 4);
    int*   cursor  = (int*)alloc((size_t)N * 4);
    int*   bsum    = (int*)alloc((size_t)64 * 4);
    int*   csr_row = (int*)alloc((size_t)E * 4);
    float* csr_val = (float*)alloc((size_t)E * 4);
    float* part    = (float*)alloc((size_t)AGG_GRID * 256 * 4);
    float* ss1     = (float*)alloc(2 * 64 * 4);
    float* ss2     = (float*)alloc(2 * 128 * 4);
    float* ss3     = (float*)alloc(2 * 128 * 4);
    float* bufA    = (float*)alloc((size_t)N * 128 * 4);
    float* bufB    = (float*)alloc((size_t)N * 128 * 4);
    (void)ws_size; (void)n_in; (void)out_size;

    const int nb_n = (N + 255) / 256;
    const int nb_e = (E + 255) / 256;
    const int nb_s = (N + 1023) / 1024;

    // CSR build (reused by all 3 layers)
    k_init_deg<<<nb_n, 256, 0, stream>>>(deg, N);
    k_count<<<nb_e, 256, 0, stream>>>(ecol, deg, E);
    k_dis<<<nb_n, 256, 0, stream>>>(deg, dis, N);
    k_scan_blk<<<nb_s, 1024, 0, stream>>>(deg, offs, bsum, N);
    k_scan_top<<<1, 64, 0, stream>>>(bsum, nb_s);
    k_scan_add<<<nb_s, 1024, 0, stream>>>(offs, cursor, bsum, N, nb_s);
    k_fill<<<nb_e, 256, 0, stream>>>(erow, ecol, dis, cursor, csr_row, csr_val, E);

    const int gemm_grid = (N + 63) / 64;

    // layer 1: x[N,128] @ W1[128,64] -> agg -> relu -> BN stats
    k_gemm<128, 64, false><<<gemm_grid, 256, 0, stream>>>(x, W1, nullptr, bufA, N);
    k_agg<64><<<AGG_GRID, 256, 0, stream>>>(bufA, offs, csr_row, csr_val, dis, b1, bufB, part, N);
    k_bnfin<64><<<1, 1024, 0, stream>>>(part, AGG_GRID, g1, bt1, ss1, N);

    // layer 2: z1[N,64] @ W2[64,128]
    k_gemm<64, 128, true><<<gemm_grid, 256, 0, stream>>>(bufB, W2, ss1, bufA, N);
    k_agg<128><<<AGG_GRID, 256, 0, stream>>>(bufA, offs, csr_row, csr_val, dis, b2, bufB, part, N);
    k_bnfin<128><<<1, 1024, 0, stream>>>(part, AGG_GRID, g2, bt2, ss2, N);

    // layer 3: z2[N,128] @ W3[128,128]
    k_gemm<128, 128, true><<<gemm_grid, 256, 0, stream>>>(bufB, W3, ss2, bufA, N);
    k_agg<128><<<AGG_GRID, 256, 0, stream>>>(bufA, offs, csr_row, csr_val, dis, b3, bufB, part, N);
    k_bnfin<128><<<1, 1024, 0, stream>>>(part, AGG_GRID, g3, bt3, ss3, N);

    // edge-pair scoring
    const int score_grid = (P + 31) / 32;
    k_score<<<score_grid, 256, 0, stream>>>(bufB, ss3, src, dst, fcW1, fcb1, fcW2, fcb2, out, P);
}

// Round 3
// 1134.741 us; speedup vs baseline: 2.1462x; 1.1269x over previous
//
#include <hip/hip_runtime.h>
#include <math.h>

// ---------------- CSR build ----------------

__global__ __launch_bounds__(256) void k_init_deg(int* deg, int n) {
    int i = blockIdx.x * 256 + threadIdx.x;
    if (i < n) deg[i] = 1;  // self-loop
}

__global__ __launch_bounds__(256) void k_count(const int* __restrict__ col, int* deg, int E) {
    int e = blockIdx.x * 256 + threadIdx.x;
    if (e < E) atomicAdd(&deg[col[e]], 1);
}

__global__ __launch_bounds__(256) void k_dis(const int* __restrict__ deg, float* __restrict__ dis, int n) {
    int i = blockIdx.x * 256 + threadIdx.x;
    if (i < n) dis[i] = 1.0f / sqrtf((float)deg[i]);
}

// hierarchical exclusive scan of (deg[i]-1) -> offs[0..n] + cursor copy
__global__ __launch_bounds__(1024) void k_scan_blk(const int* __restrict__ deg,
                                                   int* __restrict__ offs, int* __restrict__ bsum, int n) {
    __shared__ int tmp[1024];
    int i = blockIdx.x * 1024 + threadIdx.x;
    int v = (i < n) ? (deg[i] - 1) : 0;
    tmp[threadIdx.x] = v;
    __syncthreads();
    for (int off = 1; off < 1024; off <<= 1) {
        int t = (threadIdx.x >= off) ? tmp[threadIdx.x - off] : 0;
        __syncthreads();
        tmp[threadIdx.x] += t;
        __syncthreads();
    }
    if (i < n) offs[i] = tmp[threadIdx.x] - v;   // block-local exclusive
    if (threadIdx.x == 1023) bsum[blockIdx.x] = tmp[1023];
}

__global__ void k_scan_top(int* bsum, int nb) {
    if (threadIdx.x == 0) {
        int acc = 0;
        for (int b = 0; b < nb; b++) { int t = bsum[b]; bsum[b] = acc; acc += t; }
        bsum[nb] = acc;
    }
}

__global__ __launch_bounds__(1024) void k_scan_add(int* __restrict__ offs, int* __restrict__ cursor,
                                                   const int* __restrict__ bsum, int n, int nb) {
    int i = blockIdx.x * 1024 + threadIdx.x;
    if (i < n) {
        int v = offs[i] + bsum[blockIdx.x];
        offs[i] = v;
        cursor[i] = v;
    }
    if (i == 0) offs[n] = bsum[nb];
}

__global__ __launch_bounds__(256) void k_fill(const int* __restrict__ row, const int* __restrict__ col,
                                              const float* __restrict__ dis, int* cursor,
                                              int* __restrict__ csr_row, float* __restrict__ csr_val, int E) {
    int e = blockIdx.x * 256 + threadIdx.x;
    if (e >= E) return;
    int c = col[e];
    int r = row[e];
    int pos = atomicAdd(&cursor[c], 1);
    csr_row[pos] = r;
    csr_val[pos] = dis[r];
}

// ---------------- GEMM: H = (BN? X*scale+shift : X) @ W ----------------

template <int K, int COUT, bool BN>
__global__ __launch_bounds__(256) void k_gemm(const float* __restrict__ X, const float* __restrict__ W,
                                              const float* __restrict__ ss, float* __restrict__ H, int n) {
    __shared__ float Xs[64][64 + 1];
    __shared__ float Ws[64][COUT];
    const int rb = blockIdx.x * 64;
    const int tx = threadIdx.x & 15;
    const int ty = threadIdx.x >> 4;
    constexpr int CPT = COUT / 16;
    float acc[4][CPT];
#pragma unroll
    for (int r = 0; r < 4; r++)
#pragma unroll
        for (int c = 0; c < CPT; c++) acc[r][c] = 0.f;

    for (int kc = 0; kc < K; kc += 64) {
        {
            const float4* Wv = (const float4*)(W + (size_t)kc * COUT);
            float4* Wsv = (float4*)&Ws[0][0];
            for (int i = threadIdx.x; i < 64 * COUT / 4; i += 256) Wsv[i] = Wv[i];
        }
        {
            const float4* Xv = (const float4*)X;
            for (int i = threadIdx.x; i < 64 * 16; i += 256) {
                int r = i >> 4, kq = i & 15;
                int gr = rb + r;
                float4 v;
                if (gr < n) v = Xv[(size_t)gr * (K / 4) + (kc / 4) + kq];
                else { v.x = v.y = v.z = v.w = 0.f; }
                int k0 = kc + kq * 4;
                if (BN) {
                    v.x = v.x * ss[k0]     + ss[K + k0];
                    v.y = v.y * ss[k0 + 1] + ss[K + k0 + 1];
                    v.z = v.z * ss[k0 + 2] + ss[K + k0 + 2];
                    v.w = v.w * ss[k0 + 3] + ss[K + k0 + 3];
                }
                int kl = kq * 4;
                Xs[r][kl] = v.x; Xs[r][kl + 1] = v.y; Xs[r][kl + 2] = v.z; Xs[r][kl + 3] = v.w;
            }
        }
        __syncthreads();
#pragma unroll 2
        for (int k = 0; k < 64; ++k) {
            float xv[4];
#pragma unroll
            for (int r = 0; r < 4; r++) xv[r] = Xs[ty * 4 + r][k];
#pragma unroll
            for (int c = 0; c < CPT; c++) {
                float wv = Ws[k][c * 16 + tx];
#pragma unroll
                for (int r = 0; r < 4; r++) acc[r][c] += xv[r] * wv;
            }
        }
        __syncthreads();
    }
#pragma unroll
    for (int r = 0; r < 4; r++) {
        int gr = rb + ty * 4 + r;
        if (gr < n) {
#pragma unroll
            for (int c = 0; c < CPT; c++) H[(size_t)gr * COUT + c * 16 + tx] = acc[r][c];
        }
    }
}

// ---------------- aggregation + bias + ReLU + BN partial stats ----------------

template <int C>
__global__ __launch_bounds__(256) void k_agg(const float* __restrict__ H, const int* __restrict__ offs,
                                             const int* __restrict__ csr_row, const float* __restrict__ csr_val,
                                             const float* __restrict__ dis, const float* __restrict__ bias,
                                             float* __restrict__ Y, float* __restrict__ part, int n) {
    constexpr int VPL = C / 64;   // 1 or 2 channels per lane
    const int lane = threadIdx.x & 63;
    const int wave = threadIdx.x >> 6;
    const int gw = blockIdx.x * 4 + wave;
    const int nw = gridDim.x * 4;
    float bsum[VPL], bsq[VPL], bias_r[VPL];
#pragma unroll
    for (int q = 0; q < VPL; q++) { bsum[q] = 0.f; bsq[q] = 0.f; bias_r[q] = bias[lane * VPL + q]; }

    for (int node = gw; node < n; node += nw) {
        int s0 = offs[node], s1 = offs[node + 1];
        float a[VPL];
#pragma unroll
        for (int q = 0; q < VPL; q++) a[q] = 0.f;
        int e = s0;
        for (; e + 2 <= s1; e += 2) {
            int r0 = csr_row[e], r1 = csr_row[e + 1];
            float v0 = csr_val[e], v1 = csr_val[e + 1];
            const float* hp0 = H + (size_t)r0 * C + lane * VPL;
            const float* hp1 = H + (size_t)r1 * C + lane * VPL;
            if (VPL == 2) {
                float2 h0 = *(const float2*)hp0;
                float2 h1 = *(const float2*)hp1;
                a[0] += v0 * h0.x; a[1] += v0 * h0.y;
                a[0] += v1 * h1.x; a[1] += v1 * h1.y;
            } else {
                float h0 = hp0[0], h1 = hp1[0];
                a[0] += v0 * h0 + v1 * h1;
            }
        }
        if (e < s1) {
            int r0 = csr_row[e];
            float v0 = csr_val[e];
            const float* hp0 = H + (size_t)r0 * C + lane * VPL;
            if (VPL == 2) {
                float2 h0 = *(const float2*)hp0;
                a[0] += v0 * h0.x; a[1] += v0 * h0.y;
            } else {
                a[0] += v0 * hp0[0];
            }
        }
        float dn = dis[node];
        const float* hs = H + (size_t)node * C + lane * VPL;
        float outv[VPL];
#pragma unroll
        for (int q = 0; q < VPL; q++) {
            float val = a[q] * dn + hs[q] * dn * dn + bias_r[q];
            val = fmaxf(val, 0.f);
            outv[q] = val;
            bsum[q] += val;
            bsq[q] += val * val;
        }
        float* yp = Y + (size_t)node * C + lane * VPL;
        if (VPL == 2) *(float2*)yp = make_float2(outv[0], outv[1]);
        else yp[0] = outv[0];
    }
    __shared__ float psum[4][C], psq[4][C];
#pragma unroll
    for (int q = 0; q < VPL; q++) { psum[wave][lane * VPL + q] = bsum[q]; psq[wave][lane * VPL + q] = bsq[q]; }
    __syncthreads();
    for (int c = threadIdx.x; c < C; c += 256) {
        float s = psum[0][c] + psum[1][c] + psum[2][c] + psum[3][c];
        float qq = psq[0][c] + psq[1][c] + psq[2][c] + psq[3][c];
        part[(size_t)blockIdx.x * 2 * C + c] = s;
        part[(size_t)blockIdx.x * 2 * C + C + c] = qq;
    }
}

// ---------------- BN finalize ----------------

template <int C>
__global__ __launch_bounds__(1024) void k_bnfin(const float* __restrict__ part, int nblk,
                                                const float* __restrict__ g, const float* __restrict__ bt,
                                                float* __restrict__ ss, int n) {
    constexpr int ROWS = 1024 / C;
    __shared__ float ssum[1024], ssq[1024];
    const int c = threadIdx.x % C;
    const int r = threadIdx.x / C;
    float s = 0.f, q = 0.f;
    for (int b = r; b < nblk; b += ROWS) {
        s += part[(size_t)b * 2 * C + c];
        q += part[(size_t)b * 2 * C + C + c];
    }
    ssum[threadIdx.x] = s; ssq[threadIdx.x] = q;
    __syncthreads();
    if (r == 0) {
        double S = (double)s, Q = (double)q;
        for (int rr = 1; rr < ROWS; rr++) { S += (double)ssum[rr * C + c]; Q += (double)ssq[rr * C + c]; }
        double invN = 1.0 / (double)n;
        double mu = S * invN;
        double var = Q * invN - mu * mu;
        float scale = g[c] / sqrtf((float)var + 1e-5f);
        ss[c] = scale;
        ss[C + c] = bt[c] - (float)mu * scale;
    }
}

// ---------------- edge-pair scoring MLP ----------------
// 2 waves/block, 16 pairs/wave. W1 from global (L2-hot) with 8-deep double-buffered
// register prefetch. Per-wave emb tile [256][20] in LDS (20KB/wave, 40KB/block ->
// 4 blocks/CU). Gather 4 pairs into regs then ds_write_b128 (fewer, milder conflicts).
// Rows padded to 20 floats (80B) keeps float4 reads 16B-aligned.

__global__ __launch_bounds__(128) void k_score(const float* __restrict__ Y3, const float* __restrict__ ss,
                                               const int* __restrict__ src, const int* __restrict__ dst,
                                               const float* __restrict__ fcW1, const float* __restrict__ fcb1,
                                               const float* __restrict__ fcW2, const float* __restrict__ fcb2,
                                               float* __restrict__ out, int P) {
    __shared__ float embs[2][256][20];
    const int lane = threadIdx.x & 63;
    const int wave = threadIdx.x >> 6;
    const int c0 = 2 * lane;
    const float2 b1v = *(const float2*)&fcb1[c0];
    const float2 w2v = *(const float2*)&fcW2[c0];
    const float b2v = fcb2[0];
    const float sc0 = ss[lane], sc1 = ss[64 + lane];
    const float sh0 = ss[128 + lane], sh1 = ss[192 + lane];
    const int pbase = (blockIdx.x * 2 + wave) * 16;
    float (*E)[20] = embs[wave];

    // gather + BN fold, transposed into LDS, 4 pairs per b128 write
#pragma unroll
    for (int pq = 0; pq < 4; ++pq) {
        float4 r0, r1, r2, r3;
#pragma unroll
        for (int j = 0; j < 4; ++j) {
            int pi = pbase + pq * 4 + j;
            int is = 0, id = 0;
            if (pi < P) { is = src[pi]; id = dst[pi]; }
            ((float*)&r0)[j] = Y3[(size_t)is * 128 + lane] * sc0 + sh0;
            ((float*)&r1)[j] = Y3[(size_t)is * 128 + 64 + lane] * sc1 + sh1;
            ((float*)&r2)[j] = Y3[(size_t)id * 128 + lane] * sc0 + sh0;
            ((float*)&r3)[j] = Y3[(size_t)id * 128 + 64 + lane] * sc1 + sh1;
        }
        *(float4*)&E[lane][pq * 4] = r0;
        *(float4*)&E[64 + lane][pq * 4] = r1;
        *(float4*)&E[128 + lane][pq * 4] = r2;
        *(float4*)&E[192 + lane][pq * 4] = r3;
    }

    float acc0[16], acc1[16];
#pragma unroll
    for (int p = 0; p < 16; p++) { acc0[p] = 0.f; acc1[p] = 0.f; }

    const float2* W1v = (const float2*)fcW1 + lane;   // element (k, 2*lane)
    float2 w0[8], w1[8];
#pragma unroll
    for (int j = 0; j < 8; ++j) w0[j] = W1v[(size_t)j * 64];

#pragma unroll 1
    for (int kb = 0; kb < 256; kb += 16) {
        // prefetch k = kb+8 .. kb+15
#pragma unroll
        for (int j = 0; j < 8; ++j) w1[j] = W1v[(size_t)(kb + 8 + j) * 64];
        // compute k = kb .. kb+7 with w0
#pragma unroll
        for (int j = 0; j < 8; ++j) {
            int k = kb + j;
            float4 ea = *(const float4*)&E[k][0];
            float4 eb = *(const float4*)&E[k][4];
            float4 ec = *(const float4*)&E[k][8];
            float4 ed = *(const float4*)&E[k][12];
            float ev[16] = {ea.x, ea.y, ea.z, ea.w, eb.x, eb.y, eb.z, eb.w,
                            ec.x, ec.y, ec.z, ec.w, ed.x, ed.y, ed.z, ed.w};
            float wx = w0[j].x, wy = w0[j].y;
#pragma unroll
            for (int p = 0; p < 16; p++) { acc0[p] += ev[p] * wx; acc1[p] += ev[p] * wy; }
        }
        // prefetch k = kb+16 .. kb+23
        if (kb + 16 < 256) {
#pragma unroll
            for (int j = 0; j < 8; ++j) w0[j] = W1v[(size_t)(kb + 16 + j) * 64];
        }
        // compute k = kb+8 .. kb+15 with w1
#pragma unroll
        for (int j = 0; j < 8; ++j) {
            int k = kb + 8 + j;
            float4 ea = *(const float4*)&E[k][0];
            float4 eb = *(const float4*)&E[k][4];
            float4 ec = *(const float4*)&E[k][8];
            float4 ed = *(const float4*)&E[k][12];
            float ev[16] = {ea.x, ea.y, ea.z, ea.w, eb.x, eb.y, eb.z, eb.w,
                            ec.x, ec.y, ec.z, ec.w, ed.x, ed.y, ed.z, ed.w};
            float wx = w1[j].x, wy = w1[j].y;
#pragma unroll
            for (int p = 0; p < 16; p++) { acc0[p] += ev[p] * wx; acc1[p] += ev[p] * wy; }
        }
    }

#pragma unroll
    for (int p = 0; p < 16; ++p) {
        float h0 = fmaxf(acc0[p] + b1v.x, 0.f);
        float h1 = fmaxf(acc1[p] + b1v.y, 0.f);
        float s = h0 * w2v.x + h1 * w2v.y;
#pragma unroll
        for (int off = 32; off; off >>= 1) s += __shfl_xor(s, off);
        int pi = pbase + p;
        if (lane == 0 && pi < P) out[pi] = s + b2v;
    }
}

// ---------------- launch ----------------

extern "C" void kernel_launch(void* const* d_in, const int* in_sizes, int n_in,
                              void* d_out, int out_size, void* d_ws, size_t ws_size,
                              hipStream_t stream) {
    const float* x   = (const float*)d_in[0];
    const int* ei    = (const int*)d_in[1];
    const int* src   = (const int*)d_in[2];
    const int* dst   = (const int*)d_in[3];
    const float* W1  = (const float*)d_in[4];
    const float* b1  = (const float*)d_in[5];
    const float* W2  = (const float*)d_in[6];
    const float* b2  = (const float*)d_in[7];
    const float* W3  = (const float*)d_in[8];
    const float* b3  = (const float*)d_in[9];
    const float* g1  = (const float*)d_in[10];
    const float* bt1 = (const float*)d_in[11];
    const float* g2  = (const float*)d_in[12];
    const float* bt2 = (const float*)d_in[13];
    const float* g3  = (const float*)d_in[14];
    const float* bt3 = (const float*)d_in[15];
    const float* fcW1 = (const float*)d_in[16];
    const float* fcb1 = (const float*)d_in[17];
    const float* fcW2 = (const float*)d_in[18];
    const float* fcb2 = (const float*)d_in[19];
    float* out = (float*)d_out;

    const int N = in_sizes[0] / 128;   // 50000
    const int E = in_sizes[1] / 2;     // 1600000
    const int P = in_sizes[2];         // 200000
    const int* erow = ei;
    const int* ecol = ei + E;

    const int AGG_GRID = 2048;

    // workspace carve (256B aligned)
    char* w = (char*)d_ws;
    auto alloc = [&](size_t bytes) { void* p = (void*)w; w += (bytes + 255) & ~(size_t)255; return p; };
    int*   deg     = (int*)alloc((size_t)N * 4);
    float* dis     = (float*)alloc((size_t)N * 4);
    int*   offs    = (int*)alloc((size_t)(N + 1) * 4);
    int*   cursor  = (int*)alloc((size_t)N * 4);
    int*   bsum    = (int*)alloc((size_t)64 * 4);
    int*   csr_row = (int*)alloc((size_t)E * 4);
    float* csr_val = (float*)alloc((size_t)E * 4);
    float* part    = (float*)alloc((size_t)AGG_GRID * 256 * 4);
    float* ss1     = (float*)alloc(2 * 64 * 4);
    float* ss2     = (float*)alloc(2 * 128 * 4);
    float* ss3     = (float*)alloc(2 * 128 * 4);
    float* bufA    = (float*)alloc((size_t)N * 128 * 4);
    float* bufB    = (float*)alloc((size_t)N * 128 * 4);
    (void)ws_size; (void)n_in; (void)out_size;

    const int nb_n = (N + 255) / 256;
    const int nb_e = (E + 255) / 256;
    const int nb_s = (N + 1023) / 1024;

    // CSR build (reused by all 3 layers)
    k_init_deg<<<nb_n, 256, 0, stream>>>(deg, N);
    k_count<<<nb_e, 256, 0, stream>>>(ecol, deg, E);
    k_dis<<<nb_n, 256, 0, stream>>>(deg, dis, N);
    k_scan_blk<<<nb_s, 1024, 0, stream>>>(deg, offs, bsum, N);
    k_scan_top<<<1, 64, 0, stream>>>(bsum, nb_s);
    k_scan_add<<<nb_s, 1024, 0, stream>>>(offs, cursor, bsum, N, nb_s);
    k_fill<<<nb_e, 256, 0, stream>>>(erow, ecol, dis, cursor, csr_row, csr_val, E);

    const int gemm_grid = (N + 63) / 64;

    // layer 1: x[N,128] @ W1[128,64] -> agg -> relu -> BN stats
    k_gemm<128, 64, false><<<gemm_grid, 256, 0, stream>>>(x, W1, nullptr, bufA, N);
    k_agg<64><<<AGG_GRID, 256, 0, stream>>>(bufA, offs, csr_row, csr_val, dis, b1, bufB, part, N);
    k_bnfin<64><<<1, 1024, 0, stream>>>(part, AGG_GRID, g1, bt1, ss1, N);

    // layer 2: z1[N,64] @ W2[64,128]
    k_gemm<64, 128, true><<<gemm_grid, 256, 0, stream>>>(bufB, W2, ss1, bufA, N);
    k_agg<128><<<AGG_GRID, 256, 0, stream>>>(bufA, offs, csr_row, csr_val, dis, b2, bufB, part, N);
    k_bnfin<128><<<1, 1024, 0, stream>>>(part, AGG_GRID, g2, bt2, ss2, N);

    // layer 3: z2[N,128] @ W3[128,128]
    k_gemm<128, 128, true><<<gemm_grid, 256, 0, stream>>>(bufB, W3, ss2, bufA, N);
    k_agg<128><<<AGG_GRID, 256, 0, stream>>>(bufA, offs, csr_row, csr_val, dis, b3, bufB, part, N);
    k_bnfin<128><<<1, 1024, 0, stream>>>(part, AGG_GRID, g3, bt3, ss3, N);

    // edge-pair scoring: 32 pairs per 128-thread block
    const int score_grid = (P + 31) / 32;
    k_score<<<score_grid, 128, 0, stream>>>(bufB, ss3, src, dst, fcW1, fcb1, fcW2, fcb2, out, P);
}

// Round 4
// 866.946 us; speedup vs baseline: 2.8091x; 1.3089x over previous
//
#include <hip/hip_runtime.h>
#include <math.h>

typedef short bf16x8 __attribute__((ext_vector_type(8)));
typedef float f32x4 __attribute__((ext_vector_type(4)));

__device__ inline unsigned int f2bf_pack(float lo, float hi) {
    unsigned int ul = __builtin_bit_cast(unsigned int, lo);
    unsigned int uh = __builtin_bit_cast(unsigned int, hi);
    ul = ul + 0x7fffu + ((ul >> 16) & 1u);
    uh = uh + 0x7fffu + ((uh >> 16) & 1u);
    return (ul >> 16) | (uh & 0xffff0000u);
}

// ---------------- CSR build ----------------

__global__ __launch_bounds__(256) void k_init_deg(int* deg, int n) {
    int i = blockIdx.x * 256 + threadIdx.x;
    if (i < n) deg[i] = 1;  // self-loop
}

__global__ __launch_bounds__(256) void k_count(const int* __restrict__ col, int* deg, int E) {
    int e = blockIdx.x * 256 + threadIdx.x;
    if (e < E) atomicAdd(&deg[col[e]], 1);
}

__global__ __launch_bounds__(256) void k_dis(const int* __restrict__ deg, float* __restrict__ dis, int n) {
    int i = blockIdx.x * 256 + threadIdx.x;
    if (i < n) dis[i] = 1.0f / sqrtf((float)deg[i]);
}

__global__ __launch_bounds__(1024) void k_scan_blk(const int* __restrict__ deg,
                                                   int* __restrict__ offs, int* __restrict__ bsum, int n) {
    __shared__ int tmp[1024];
    int i = blockIdx.x * 1024 + threadIdx.x;
    int v = (i < n) ? (deg[i] - 1) : 0;
    tmp[threadIdx.x] = v;
    __syncthreads();
    for (int off = 1; off < 1024; off <<= 1) {
        int t = (threadIdx.x >= off) ? tmp[threadIdx.x - off] : 0;
        __syncthreads();
        tmp[threadIdx.x] += t;
        __syncthreads();
    }
    if (i < n) offs[i] = tmp[threadIdx.x] - v;
    if (threadIdx.x == 1023) bsum[blockIdx.x] = tmp[1023];
}

__global__ void k_scan_top(int* bsum, int nb) {
    if (threadIdx.x == 0) {
        int acc = 0;
        for (int b = 0; b < nb; b++) { int t = bsum[b]; bsum[b] = acc; acc += t; }
        bsum[nb] = acc;
    }
}

__global__ __launch_bounds__(1024) void k_scan_add(int* __restrict__ offs, int* __restrict__ cursor,
                                                   const int* __restrict__ bsum, int n, int nb) {
    int i = blockIdx.x * 1024 + threadIdx.x;
    if (i < n) {
        int v = offs[i] + bsum[blockIdx.x];
        offs[i] = v;
        cursor[i] = v;
    }
    if (i == 0) offs[n] = bsum[nb];
}

__global__ __launch_bounds__(256) void k_fill(const int* __restrict__ row, const int* __restrict__ col,
                                              const float* __restrict__ dis, int* cursor,
                                              int* __restrict__ csr_row, float* __restrict__ csr_val, int E) {
    int e = blockIdx.x * 256 + threadIdx.x;
    if (e >= E) return;
    int c = col[e];
    int r = row[e];
    int pos = atomicAdd(&cursor[c], 1);
    csr_row[pos] = r;
    csr_val[pos] = dis[r];
}

// ---------------- W1 -> bf16 B-fragment tiles ----------------
// layout: group g=(nt*8+ks)*64+l holds 8 bf16: B[k = ks*32+(l>>4)*8+j][n = nt*16+(l&15)]

__global__ __launch_bounds__(256) void k_prepw(const float* __restrict__ fcW1, unsigned short* __restrict__ Wt) {
    int g = blockIdx.x * 256 + threadIdx.x;   // 0..4095
    if (g >= 4096) return;
    int l = g & 63, ks = (g >> 6) & 7, nt = g >> 9;
    int n = nt * 16 + (l & 15);
    int k0 = ks * 32 + (l >> 4) * 8;
    unsigned int w[4];
#pragma unroll
    for (int j = 0; j < 4; ++j) {
        float a = fcW1[(size_t)(k0 + 2 * j) * 128 + n];
        float b = fcW1[(size_t)(k0 + 2 * j + 1) * 128 + n];
        w[j] = f2bf_pack(a, b);
    }
    *(uint4*)(Wt + (size_t)g * 8) = make_uint4(w[0], w[1], w[2], w[3]);
}

// ---------------- GEMM (plain): H = X @ W ----------------

template <int K, int COUT>
__global__ __launch_bounds__(256) void k_gemm(const float* __restrict__ X, const float* __restrict__ W,
                                              float* __restrict__ H, int n) {
    __shared__ float Xs[64][64 + 1];
    __shared__ float Ws[64][COUT];
    const int rb = blockIdx.x * 64;
    const int tx = threadIdx.x & 15;
    const int ty = threadIdx.x >> 4;
    constexpr int CPT = COUT / 16;
    float acc[4][CPT];
#pragma unroll
    for (int r = 0; r < 4; r++)
#pragma unroll
        for (int c = 0; c < CPT; c++) acc[r][c] = 0.f;

    for (int kc = 0; kc < K; kc += 64) {
        {
            const float4* Wv = (const float4*)(W + (size_t)kc * COUT);
            float4* Wsv = (float4*)&Ws[0][0];
            for (int i = threadIdx.x; i < 64 * COUT / 4; i += 256) Wsv[i] = Wv[i];
        }
        {
            const float4* Xv = (const float4*)X;
            for (int i = threadIdx.x; i < 64 * 16; i += 256) {
                int r = i >> 4, kq = i & 15;
                int gr = rb + r;
                float4 v;
                if (gr < n) v = Xv[(size_t)gr * (K / 4) + (kc / 4) + kq];
                else { v.x = v.y = v.z = v.w = 0.f; }
                int kl = kq * 4;
                Xs[r][kl] = v.x; Xs[r][kl + 1] = v.y; Xs[r][kl + 2] = v.z; Xs[r][kl + 3] = v.w;
            }
        }
        __syncthreads();
#pragma unroll 2
        for (int k = 0; k < 64; ++k) {
            float xv[4];
#pragma unroll
            for (int r = 0; r < 4; r++) xv[r] = Xs[ty * 4 + r][k];
#pragma unroll
            for (int c = 0; c < CPT; c++) {
                float wv = Ws[k][c * 16 + tx];
#pragma unroll
                for (int r = 0; r < 4; r++) acc[r][c] += xv[r] * wv;
            }
        }
        __syncthreads();
    }
#pragma unroll
    for (int r = 0; r < 4; r++) {
        int gr = rb + ty * 4 + r;
        if (gr < n) {
#pragma unroll
            for (int c = 0; c < CPT; c++) H[(size_t)gr * COUT + c * 16 + tx] = acc[r][c];
        }
    }
}

// ---------------- GEMM fused: H = relu(X@W + b), + BN partial stats ----------------

template <int K, int COUT>
__global__ __launch_bounds__(256) void k_gemmf(const float* __restrict__ X, const float* __restrict__ W,
                                               const float* __restrict__ bias, float* __restrict__ H,
                                               float* __restrict__ part, int n) {
    __shared__ float Xs[64][64 + 1];
    __shared__ float Ws[64][COUT];
    const int rb = blockIdx.x * 64;
    const int tx = threadIdx.x & 15;
    const int ty = threadIdx.x >> 4;
    constexpr int CPT = COUT / 16;
    float acc[4][CPT];
#pragma unroll
    for (int r = 0; r < 4; r++)
#pragma unroll
        for (int c = 0; c < CPT; c++) acc[r][c] = 0.f;

    for (int kc = 0; kc < K; kc += 64) {
        {
            const float4* Wv = (const float4*)(W + (size_t)kc * COUT);
            float4* Wsv = (float4*)&Ws[0][0];
            for (int i = threadIdx.x; i < 64 * COUT / 4; i += 256) Wsv[i] = Wv[i];
        }
        {
            const float4* Xv = (const float4*)X;
            for (int i = threadIdx.x; i < 64 * 16; i += 256) {
                int r = i >> 4, kq = i & 15;
                int gr = rb + r;
                float4 v;
                if (gr < n) v = Xv[(size_t)gr * (K / 4) + (kc / 4) + kq];
                else { v.x = v.y = v.z = v.w = 0.f; }
                int kl = kq * 4;
                Xs[r][kl] = v.x; Xs[r][kl + 1] = v.y; Xs[r][kl + 2] = v.z; Xs[r][kl + 3] = v.w;
            }
        }
        __syncthreads();
#pragma unroll 2
        for (int k = 0; k < 64; ++k) {
            float xv[4];
#pragma unroll
            for (int r = 0; r < 4; r++) xv[r] = Xs[ty * 4 + r][k];
#pragma unroll
            for (int c = 0; c < CPT; c++) {
                float wv = Ws[k][c * 16 + tx];
#pragma unroll
                for (int r = 0; r < 4; r++) acc[r][c] += xv[r] * wv;
            }
        }
        __syncthreads();
    }
    // epilogue: bias + relu + store + per-block channel stats (reuse LDS)
    float* tsum = &Xs[0][0];   // 16*COUT floats
    float* tsq  = &Ws[0][0];
    float vs[CPT], vq[CPT];
#pragma unroll
    for (int c = 0; c < CPT; c++) { vs[c] = 0.f; vq[c] = 0.f; }
#pragma unroll
    for (int r = 0; r < 4; r++) {
        int gr = rb + ty * 4 + r;
        bool ok = gr < n;
#pragma unroll
        for (int c = 0; c < CPT; c++) {
            float val = ok ? fmaxf(acc[r][c] + bias[c * 16 + tx], 0.f) : 0.f;
            if (ok) H[(size_t)gr * COUT + c * 16 + tx] = val;
            vs[c] += val;
            vq[c] += val * val;
        }
    }
#pragma unroll
    for (int c = 0; c < CPT; c++) {
        tsum[ty * COUT + c * 16 + tx] = vs[c];
        tsq[ty * COUT + c * 16 + tx] = vq[c];
    }
    __syncthreads();
    for (int col = threadIdx.x; col < COUT; col += 256) {
        float S = 0.f, Q = 0.f;
#pragma unroll 4
        for (int t = 0; t < 16; t++) { S += tsum[t * COUT + col]; Q += tsq[t * COUT + col]; }
        part[(size_t)blockIdx.x * 2 * COUT + col] = S;
        part[(size_t)blockIdx.x * 2 * COUT + COUT + col] = Q;
    }
}

// ---------------- aggregation post-GEMM (layer 1): bias+relu+stats ----------------

template <int C>
__global__ __launch_bounds__(256) void k_agg(const float* __restrict__ H, const int* __restrict__ offs,
                                             const int* __restrict__ csr_row, const float* __restrict__ csr_val,
                                             const float* __restrict__ dis, const float* __restrict__ bias,
                                             float* __restrict__ Y, float* __restrict__ part, int n) {
    constexpr int VPL = C / 64;
    const int lane = threadIdx.x & 63;
    const int wave = threadIdx.x >> 6;
    const int gw = blockIdx.x * 4 + wave;
    const int nw = gridDim.x * 4;
    float bsum[VPL], bsq[VPL], bias_r[VPL];
#pragma unroll
    for (int q = 0; q < VPL; q++) { bsum[q] = 0.f; bsq[q] = 0.f; bias_r[q] = bias[lane * VPL + q]; }

    for (int node = gw; node < n; node += nw) {
        int s0 = offs[node], s1 = offs[node + 1];
        float a[VPL];
#pragma unroll
        for (int q = 0; q < VPL; q++) a[q] = 0.f;
        int e = s0;
        for (; e + 2 <= s1; e += 2) {
            int r0 = csr_row[e], r1 = csr_row[e + 1];
            float v0 = csr_val[e], v1 = csr_val[e + 1];
            const float* hp0 = H + (size_t)r0 * C + lane * VPL;
            const float* hp1 = H + (size_t)r1 * C + lane * VPL;
            if (VPL == 2) {
                float2 h0 = *(const float2*)hp0;
                float2 h1 = *(const float2*)hp1;
                a[0] += v0 * h0.x; a[1] += v0 * h0.y;
                a[0] += v1 * h1.x; a[1] += v1 * h1.y;
            } else {
                a[0] += v0 * hp0[0] + v1 * hp1[0];
            }
        }
        if (e < s1) {
            int r0 = csr_row[e];
            float v0 = csr_val[e];
            const float* hp0 = H + (size_t)r0 * C + lane * VPL;
            if (VPL == 2) {
                float2 h0 = *(const float2*)hp0;
                a[0] += v0 * h0.x; a[1] += v0 * h0.y;
            } else {
                a[0] += v0 * hp0[0];
            }
        }
        float dn = dis[node];
        const float* hs = H + (size_t)node * C + lane * VPL;
        float outv[VPL];
#pragma unroll
        for (int q = 0; q < VPL; q++) {
            float val = a[q] * dn + hs[q] * dn * dn + bias_r[q];
            val = fmaxf(val, 0.f);
            outv[q] = val;
            bsum[q] += val;
            bsq[q] += val * val;
        }
        float* yp = Y + (size_t)node * C + lane * VPL;
        if (VPL == 2) *(float2*)yp = make_float2(outv[0], outv[1]);
        else yp[0] = outv[0];
    }
    __shared__ float psum[4][C], psq[4][C];
#pragma unroll
    for (int q = 0; q < VPL; q++) { psum[wave][lane * VPL + q] = bsum[q]; psq[wave][lane * VPL + q] = bsq[q]; }
    __syncthreads();
    for (int c = threadIdx.x; c < C; c += 256) {
        float s = psum[0][c] + psum[1][c] + psum[2][c] + psum[3][c];
        float qq = psq[0][c] + psq[1][c] + psq[2][c] + psq[3][c];
        part[(size_t)blockIdx.x * 2 * C + c] = s;
        part[(size_t)blockIdx.x * 2 * C + C + c] = qq;
    }
}

// ---------------- aggregation pre-GEMM (layers 2,3): BN fold via scale/shift ----------------
// out[v][c] = dn * ( (A_c + dn*in[v][c])*sc_c + (S + dn)*sh_c ),  A_c = sum val*in, S = sum val

template <int C>
__global__ __launch_bounds__(256) void k_aggpre(const float* __restrict__ IN, const int* __restrict__ offs,
                                                const int* __restrict__ csr_row, const float* __restrict__ csr_val,
                                                const float* __restrict__ dis, const float* __restrict__ ss,
                                                float* __restrict__ OUT, int n) {
    constexpr int VPL = C / 64;
    const int lane = threadIdx.x & 63;
    const int wave = threadIdx.x >> 6;
    const int gw = blockIdx.x * 4 + wave;
    const int nw = gridDim.x * 4;
    float sc[VPL], sh[VPL];
#pragma unroll
    for (int q = 0; q < VPL; q++) { sc[q] = ss[lane * VPL + q]; sh[q] = ss[C + lane * VPL + q]; }

    for (int node = gw; node < n; node += nw) {
        int s0 = offs[node], s1 = offs[node + 1];
        float a[VPL];
        float S = 0.f;
#pragma unroll
        for (int q = 0; q < VPL; q++) a[q] = 0.f;
        int e = s0;
        for (; e + 2 <= s1; e += 2) {
            int r0 = csr_row[e], r1 = csr_row[e + 1];
            float v0 = csr_val[e], v1 = csr_val[e + 1];
            S += v0 + v1;
            const float* hp0 = IN + (size_t)r0 * C + lane * VPL;
            const float* hp1 = IN + (size_t)r1 * C + lane * VPL;
            if (VPL == 2) {
                float2 h0 = *(const float2*)hp0;
                float2 h1 = *(const float2*)hp1;
                a[0] += v0 * h0.x; a[1] += v0 * h0.y;
                a[0] += v1 * h1.x; a[1] += v1 * h1.y;
            } else {
                a[0] += v0 * hp0[0] + v1 * hp1[0];
            }
        }
        if (e < s1) {
            int r0 = csr_row[e];
            float v0 = csr_val[e];
            S += v0;
            const float* hp0 = IN + (size_t)r0 * C + lane * VPL;
            if (VPL == 2) {
                float2 h0 = *(const float2*)hp0;
                a[0] += v0 * h0.x; a[1] += v0 * h0.y;
            } else {
                a[0] += v0 * hp0[0];
            }
        }
        float dn = dis[node];
        float shf = (S + dn);
        const float* hs = IN + (size_t)node * C + lane * VPL;
        float outv[VPL];
#pragma unroll
        for (int q = 0; q < VPL; q++) {
            outv[q] = dn * ((a[q] + dn * hs[q]) * sc[q] + shf * sh[q]);
        }
        float* yp = OUT + (size_t)node * C + lane * VPL;
        if (VPL == 2) *(float2*)yp = make_float2(outv[0], outv[1]);
        else yp[0] = outv[0];
    }
}

// ---------------- BN finalize ----------------

template <int C>
__global__ __launch_bounds__(1024) void k_bnfin(const float* __restrict__ part, int nblk,
                                                const float* __restrict__ g, const float* __restrict__ bt,
                                                float* __restrict__ ss, int n) {
    constexpr int ROWS = 1024 / C;
    __shared__ float ssum[1024], ssq[1024];
    const int c = threadIdx.x % C;
    const int r = threadIdx.x / C;
    float s = 0.f, q = 0.f;
    for (int b = r; b < nblk; b += ROWS) {
        s += part[(size_t)b * 2 * C + c];
        q += part[(size_t)b * 2 * C + C + c];
    }
    ssum[threadIdx.x] = s; ssq[threadIdx.x] = q;
    __syncthreads();
    if (r == 0) {
        double S = (double)s, Q = (double)q;
        for (int rr = 1; rr < ROWS; rr++) { S += (double)ssum[rr * C + c]; Q += (double)ssq[rr * C + c]; }
        double invN = 1.0 / (double)n;
        double mu = S * invN;
        double var = Q * invN - mu * mu;
        float scale = g[c] / sqrtf((float)var + 1e-5f);
        ss[c] = scale;
        ss[C + c] = bt[c] - (float)mu * scale;
    }
}

// ---------------- edge-pair scoring via MFMA ----------------
// 2 waves/block, 16 pairs/wave. emb gathered+BN-folded, packed bf16 into XOR-swizzled
// per-wave LDS tile [16 pairs][256 k] (8KB). A-frags: ds_read_b128 (lane: m=l&15,
// k0=(l>>4)*8). B-frags: W1 pre-tiled bf16 (k_prepw), fully-coalesced dwordx4.
// C layout (verified m89): col=lane&15 (out), row=(lane>>4)*4+reg (pair).

__global__ __launch_bounds__(128) void k_score(const float* __restrict__ Z, const float* __restrict__ ss,
                                               const int* __restrict__ src, const int* __restrict__ dst,
                                               const unsigned short* __restrict__ Wt,
                                               const float* __restrict__ fcb1, const float* __restrict__ fcW2,
                                               const float* __restrict__ fcb2, float* __restrict__ out, int P) {
    __shared__ unsigned int emb[2][16][128];   // [wave][pair][u32 = 2 bf16] = 16KB
    const int lane = threadIdx.x & 63;
    const int wave = threadIdx.x >> 6;
    unsigned int (*Ew)[128] = emb[wave];
    const int tile = blockIdx.x * 2 + wave;
    const int pbase = tile * 16;

    const float2 sc2 = *(const float2*)&ss[2 * lane];
    const float2 sh2 = *(const float2*)&ss[128 + 2 * lane];

    // gather + BN fold + bf16 pack into swizzled LDS
#pragma unroll 4
    for (int p = 0; p < 16; ++p) {
        int pi = pbase + p;
        int is = src[pi], id = dst[pi];
        float2 a = *(const float2*)&Z[(size_t)is * 128 + 2 * lane];
        float2 b = *(const float2*)&Z[(size_t)id * 128 + 2 * lane];
        unsigned int ua = f2bf_pack(a.x * sc2.x + sh2.x, a.y * sc2.y + sh2.y);
        unsigned int ub = f2bf_pack(b.x * sc2.x + sh2.x, b.y * sc2.y + sh2.y);
        int swz = (p & 7) << 4;
        char* rowp = (char*)&Ew[p][0];
        *(unsigned int*)(rowp + ((lane * 4) ^ swz)) = ua;
        *(unsigned int*)(rowp + (((lane + 64) * 4) ^ swz)) = ub;
    }

    // A fragments: 8 K-steps
    const int m = lane & 15;
    const int g4 = lane >> 4;
    bf16x8 af[8];
    {
        const char* rowp = (const char*)&Ew[m][0];
        const int sw = (m & 7) << 4;
#pragma unroll
        for (int ks = 0; ks < 8; ++ks)
            af[ks] = *(const bf16x8*)(rowp + ((ks * 64 + g4 * 16) ^ sw));
    }

    float sacc[4] = {0.f, 0.f, 0.f, 0.f};
    const bf16x8* Wtv = (const bf16x8*)Wt;
#pragma unroll 2
    for (int nt = 0; nt < 8; ++nt) {
        f32x4 acc = {0.f, 0.f, 0.f, 0.f};
#pragma unroll
        for (int ks = 0; ks < 8; ++ks) {
            bf16x8 bf = Wtv[(nt * 8 + ks) * 64 + lane];
            acc = __builtin_amdgcn_mfma_f32_16x16x32_bf16(af[ks], bf, acc, 0, 0, 0);
        }
        int oc = nt * 16 + m;
        float b1 = fcb1[oc];
        float w2 = fcW2[oc];
#pragma unroll
        for (int r = 0; r < 4; ++r) {
            float h = fmaxf(acc[r] + b1, 0.f);
            sacc[r] += h * w2;
        }
    }

    const float b2v = fcb2[0];
#pragma unroll
    for (int r = 0; r < 4; ++r) {
        float s = sacc[r];
        s += __shfl_xor(s, 1);
        s += __shfl_xor(s, 2);
        s += __shfl_xor(s, 4);
        s += __shfl_xor(s, 8);
        if (m == 0) out[pbase + g4 * 4 + r] = s + b2v;
    }
}

// ---------------- launch ----------------

extern "C" void kernel_launch(void* const* d_in, const int* in_sizes, int n_in,
                              void* d_out, int out_size, void* d_ws, size_t ws_size,
                              hipStream_t stream) {
    const float* x   = (const float*)d_in[0];
    const int* ei    = (const int*)d_in[1];
    const int* src   = (const int*)d_in[2];
    const int* dst   = (const int*)d_in[3];
    const float* W1  = (const float*)d_in[4];
    const float* b1  = (const float*)d_in[5];
    const float* W2  = (const float*)d_in[6];
    const float* b2  = (const float*)d_in[7];
    const float* W3  = (const float*)d_in[8];
    const float* b3  = (const float*)d_in[9];
    const float* g1  = (const float*)d_in[10];
    const float* bt1 = (const float*)d_in[11];
    const float* g2  = (const float*)d_in[12];
    const float* bt2 = (const float*)d_in[13];
    const float* g3  = (const float*)d_in[14];
    const float* bt3 = (const float*)d_in[15];
    const float* fcW1 = (const float*)d_in[16];
    const float* fcb1 = (const float*)d_in[17];
    const float* fcW2 = (const float*)d_in[18];
    const float* fcb2 = (const float*)d_in[19];
    float* out = (float*)d_out;

    const int N = in_sizes[0] / 128;   // 50000
    const int E = in_sizes[1] / 2;     // 1600000
    const int P = in_sizes[2];         // 200000
    const int* erow = ei;
    const int* ecol = ei + E;

    const int AGG_GRID = 2048;

    char* w = (char*)d_ws;
    auto alloc = [&](size_t bytes) { void* p = (void*)w; w += (bytes + 255) & ~(size_t)255; return p; };
    int*   deg     = (int*)alloc((size_t)N * 4);
    float* dis     = (float*)alloc((size_t)N * 4);
    int*   offs    = (int*)alloc((size_t)(N + 1) * 4);
    int*   cursor  = (int*)alloc((size_t)N * 4);
    int*   bsum    = (int*)alloc((size_t)64 * 4);
    int*   csr_row = (int*)alloc((size_t)E * 4);
    float* csr_val = (float*)alloc((size_t)E * 4);
    float* part    = (float*)alloc((size_t)AGG_GRID * 256 * 4);
    float* ss1     = (float*)alloc(2 * 64 * 4);
    float* ss2     = (float*)alloc(2 * 128 * 4);
    float* ss3     = (float*)alloc(2 * 128 * 4);
    unsigned short* Wt = (unsigned short*)alloc((size_t)4096 * 8 * 2);
    float* bufA    = (float*)alloc((size_t)N * 128 * 4);
    float* bufB    = (float*)alloc((size_t)N * 128 * 4);
    (void)ws_size; (void)n_in; (void)out_size;

    const int nb_n = (N + 255) / 256;
    const int nb_e = (E + 255) / 256;
    const int nb_s = (N + 1023) / 1024;

    // CSR build + W1 tile prep
    k_init_deg<<<nb_n, 256, 0, stream>>>(deg, N);
    k_count<<<nb_e, 256, 0, stream>>>(ecol, deg, E);
    k_dis<<<nb_n, 256, 0, stream>>>(deg, dis, N);
    k_scan_blk<<<nb_s, 1024, 0, stream>>>(deg, offs, bsum, N);
    k_scan_top<<<1, 64, 0, stream>>>(bsum, nb_s);
    k_scan_add<<<nb_s, 1024, 0, stream>>>(offs, cursor, bsum, N, nb_s);
    k_fill<<<nb_e, 256, 0, stream>>>(erow, ecol, dis, cursor, csr_row, csr_val, E);
    k_prepw<<<16, 256, 0, stream>>>(fcW1, Wt);

    const int gemm_grid = (N + 63) / 64;

    // layer 1: gemm(x @ W1) -> agg(+bias,relu,stats)
    k_gemm<128, 64><<<gemm_grid, 256, 0, stream>>>(x, W1, bufA, N);
    k_agg<64><<<AGG_GRID, 256, 0, stream>>>(bufA, offs, csr_row, csr_val, dis, b1, bufB, part, N);
    k_bnfin<64><<<1, 1024, 0, stream>>>(part, AGG_GRID, g1, bt1, ss1, N);

    // layer 2: aggpre(BN1-fold, 64ch) -> gemmf(W2 +bias,relu,stats)
    k_aggpre<64><<<AGG_GRID, 256, 0, stream>>>(bufB, offs, csr_row, csr_val, dis, ss1, bufA, N);
    k_gemmf<64, 128><<<gemm_grid, 256, 0, stream>>>(bufA, W2, b2, bufB, part, N);
    k_bnfin<128><<<1, 1024, 0, stream>>>(part, gemm_grid, g2, bt2, ss2, N);

    // layer 3: aggpre(BN2-fold, 128ch) -> gemmf(W3 +bias,relu,stats)
    k_aggpre<128><<<AGG_GRID, 256, 0, stream>>>(bufB, offs, csr_row, csr_val, dis, ss2, bufA, N);
    k_gemmf<128, 128><<<gemm_grid, 256, 0, stream>>>(bufA, W3, b3, bufB, part, N);
    k_bnfin<128><<<1, 1024, 0, stream>>>(part, gemm_grid, g3, bt3, ss3, N);

    // edge-pair scoring (MFMA): 32 pairs per 128-thread block
    const int score_grid = P / 32;
    k_score<<<score_grid, 128, 0, stream>>>(bufB, ss3, src, dst, Wt, fcb1, fcW2, fcb2, out, P);
}

// Round 5
// 784.623 us; speedup vs baseline: 3.1039x; 1.1049x over previous
//
#include <hip/hip_runtime.h>
#include <math.h>

typedef short bf16x8 __attribute__((ext_vector_type(8)));
typedef float f32x4 __attribute__((ext_vector_type(4)));

__device__ inline unsigned int f2bf_pack(float lo, float hi) {
    unsigned int ul = __builtin_bit_cast(unsigned int, lo);
    unsigned int uh = __builtin_bit_cast(unsigned int, hi);
    ul = ul + 0x7fffu + ((ul >> 16) & 1u);
    uh = uh + 0x7fffu + ((uh >> 16) & 1u);
    return (ul >> 16) | (uh & 0xffff0000u);
}
__device__ inline unsigned short f2bf(float f) {
    unsigned int u = __builtin_bit_cast(unsigned int, f);
    u = u + 0x7fffu + ((u >> 16) & 1u);
    return (unsigned short)(u >> 16);
}
__device__ inline float bf2f(unsigned short u) {
    return __builtin_bit_cast(float, (unsigned int)u << 16);
}
__device__ inline float bflo(unsigned int w) { return __builtin_bit_cast(float, w << 16); }
__device__ inline float bfhi(unsigned int w) { return __builtin_bit_cast(float, w & 0xffff0000u); }

// ---------------- CSR build ----------------

__global__ __launch_bounds__(256) void k_init_deg(int* deg, int n) {
    int i = blockIdx.x * 256 + threadIdx.x;
    if (i < n) deg[i] = 1;  // self-loop
}

__global__ __launch_bounds__(256) void k_count(const int* __restrict__ col, int* deg, int E) {
    int e = blockIdx.x * 256 + threadIdx.x;
    if (e < E) atomicAdd(&deg[col[e]], 1);
}

__global__ __launch_bounds__(256) void k_dis(const int* __restrict__ deg, float* __restrict__ dis, int n) {
    int i = blockIdx.x * 256 + threadIdx.x;
    if (i < n) dis[i] = 1.0f / sqrtf((float)deg[i]);
}

__global__ __launch_bounds__(1024) void k_scan_blk(const int* __restrict__ deg,
                                                   int* __restrict__ offs, int* __restrict__ bsum, int n) {
    __shared__ int tmp[1024];
    int i = blockIdx.x * 1024 + threadIdx.x;
    int v = (i < n) ? (deg[i] - 1) : 0;
    tmp[threadIdx.x] = v;
    __syncthreads();
    for (int off = 1; off < 1024; off <<= 1) {
        int t = (threadIdx.x >= off) ? tmp[threadIdx.x - off] : 0;
        __syncthreads();
        tmp[threadIdx.x] += t;
        __syncthreads();
    }
    if (i < n) offs[i] = tmp[threadIdx.x] - v;
    if (threadIdx.x == 1023) bsum[blockIdx.x] = tmp[1023];
}

__global__ void k_scan_top(int* bsum, int nb) {
    if (threadIdx.x == 0) {
        int acc = 0;
        for (int b = 0; b < nb; b++) { int t = bsum[b]; bsum[b] = acc; acc += t; }
        bsum[nb] = acc;
    }
}

__global__ __launch_bounds__(1024) void k_scan_add(int* __restrict__ offs, int* __restrict__ cursor,
                                                   const int* __restrict__ bsum, int n, int nb) {
    int i = blockIdx.x * 1024 + threadIdx.x;
    if (i < n) {
        int v = offs[i] + bsum[blockIdx.x];
        offs[i] = v;
        cursor[i] = v;
    }
    if (i == 0) offs[n] = bsum[nb];
}

// packed CSR entry: .x = src row, .y = bitcast(dis[row]) — ONE 8B scatter per edge
__global__ __launch_bounds__(256) void k_fill(const int* __restrict__ row, const int* __restrict__ col,
                                              const float* __restrict__ dis, int* cursor,
                                              int2* __restrict__ csr, int E) {
    int e = blockIdx.x * 256 + threadIdx.x;
    if (e >= E) return;
    int c = col[e];
    int r = row[e];
    int pos = atomicAdd(&cursor[c], 1);
    csr[pos] = make_int2(r, __builtin_bit_cast(int, dis[r]));
}

// ---------------- W1 -> bf16 B-fragment tiles ----------------

__global__ __launch_bounds__(256) void k_prepw(const float* __restrict__ fcW1, unsigned short* __restrict__ Wt) {
    int g = blockIdx.x * 256 + threadIdx.x;   // 0..4095
    if (g >= 4096) return;
    int l = g & 63, ks = (g >> 6) & 7, nt = g >> 9;
    int n = nt * 16 + (l & 15);
    int k0 = ks * 32 + (l >> 4) * 8;
    unsigned int w[4];
#pragma unroll
    for (int j = 0; j < 4; ++j) {
        float a = fcW1[(size_t)(k0 + 2 * j) * 128 + n];
        float b = fcW1[(size_t)(k0 + 2 * j + 1) * 128 + n];
        w[j] = f2bf_pack(a, b);
    }
    *(uint4*)(Wt + (size_t)g * 8) = make_uint4(w[0], w[1], w[2], w[3]);
}

// ---------------- GEMM (layer 1): H = X @ W, bf16 out ----------------

template <int K, int COUT>
__global__ __launch_bounds__(256) void k_gemm(const float* __restrict__ X, const float* __restrict__ W,
                                              unsigned short* __restrict__ H, int n) {
    __shared__ float Xs[64][64 + 1];
    __shared__ float Ws[64][COUT];
    const int rb = blockIdx.x * 64;
    const int tx = threadIdx.x & 15;
    const int ty = threadIdx.x >> 4;
    constexpr int CPT = COUT / 16;
    float acc[4][CPT];
#pragma unroll
    for (int r = 0; r < 4; r++)
#pragma unroll
        for (int c = 0; c < CPT; c++) acc[r][c] = 0.f;

    for (int kc = 0; kc < K; kc += 64) {
        {
            const float4* Wv = (const float4*)(W + (size_t)kc * COUT);
            float4* Wsv = (float4*)&Ws[0][0];
            for (int i = threadIdx.x; i < 64 * COUT / 4; i += 256) Wsv[i] = Wv[i];
        }
        {
            const float4* Xv = (const float4*)X;
            for (int i = threadIdx.x; i < 64 * 16; i += 256) {
                int r = i >> 4, kq = i & 15;
                int gr = rb + r;
                float4 v;
                if (gr < n) v = Xv[(size_t)gr * (K / 4) + (kc / 4) + kq];
                else { v.x = v.y = v.z = v.w = 0.f; }
                int kl = kq * 4;
                Xs[r][kl] = v.x; Xs[r][kl + 1] = v.y; Xs[r][kl + 2] = v.z; Xs[r][kl + 3] = v.w;
            }
        }
        __syncthreads();
#pragma unroll 2
        for (int k = 0; k < 64; ++k) {
            float xv[4];
#pragma unroll
            for (int r = 0; r < 4; r++) xv[r] = Xs[ty * 4 + r][k];
#pragma unroll
            for (int c = 0; c < CPT; c++) {
                float wv = Ws[k][c * 16 + tx];
#pragma unroll
                for (int r = 0; r < 4; r++) acc[r][c] += xv[r] * wv;
            }
        }
        __syncthreads();
    }
#pragma unroll
    for (int r = 0; r < 4; r++) {
        int gr = rb + ty * 4 + r;
        if (gr < n) {
#pragma unroll
            for (int c = 0; c < CPT; c++) H[(size_t)gr * COUT + c * 16 + tx] = f2bf(acc[r][c]);
        }
    }
}

// ---------------- GEMM fused: H = relu(X@W + b) bf16, + BN partial stats ----------------

template <int K, int COUT>
__global__ __launch_bounds__(256) void k_gemmf(const float* __restrict__ X, const float* __restrict__ W,
                                               const float* __restrict__ bias, unsigned short* __restrict__ H,
                                               float* __restrict__ part, int n) {
    __shared__ float Xs[64][64 + 1];
    __shared__ float Ws[64][COUT];
    const int rb = blockIdx.x * 64;
    const int tx = threadIdx.x & 15;
    const int ty = threadIdx.x >> 4;
    constexpr int CPT = COUT / 16;
    float acc[4][CPT];
#pragma unroll
    for (int r = 0; r < 4; r++)
#pragma unroll
        for (int c = 0; c < CPT; c++) acc[r][c] = 0.f;

    for (int kc = 0; kc < K; kc += 64) {
        {
            const float4* Wv = (const float4*)(W + (size_t)kc * COUT);
            float4* Wsv = (float4*)&Ws[0][0];
            for (int i = threadIdx.x; i < 64 * COUT / 4; i += 256) Wsv[i] = Wv[i];
        }
        {
            const float4* Xv = (const float4*)X;
            for (int i = threadIdx.x; i < 64 * 16; i += 256) {
                int r = i >> 4, kq = i & 15;
                int gr = rb + r;
                float4 v;
                if (gr < n) v = Xv[(size_t)gr * (K / 4) + (kc / 4) + kq];
                else { v.x = v.y = v.z = v.w = 0.f; }
                int kl = kq * 4;
                Xs[r][kl] = v.x; Xs[r][kl + 1] = v.y; Xs[r][kl + 2] = v.z; Xs[r][kl + 3] = v.w;
            }
        }
        __syncthreads();
#pragma unroll 2
        for (int k = 0; k < 64; ++k) {
            float xv[4];
#pragma unroll
            for (int r = 0; r < 4; r++) xv[r] = Xs[ty * 4 + r][k];
#pragma unroll
            for (int c = 0; c < CPT; c++) {
                float wv = Ws[k][c * 16 + tx];
#pragma unroll
                for (int r = 0; r < 4; r++) acc[r][c] += xv[r] * wv;
            }
        }
        __syncthreads();
    }
    // epilogue: bias + relu + bf16 store + per-block channel stats (reuse LDS)
    float* tsum = &Xs[0][0];
    float* tsq  = &Ws[0][0];
    float vs[CPT], vq[CPT];
#pragma unroll
    for (int c = 0; c < CPT; c++) { vs[c] = 0.f; vq[c] = 0.f; }
#pragma unroll
    for (int r = 0; r < 4; r++) {
        int gr = rb + ty * 4 + r;
        bool ok = gr < n;
#pragma unroll
        for (int c = 0; c < CPT; c++) {
            float val = ok ? fmaxf(acc[r][c] + bias[c * 16 + tx], 0.f) : 0.f;
            if (ok) H[(size_t)gr * COUT + c * 16 + tx] = f2bf(val);
            vs[c] += val;
            vq[c] += val * val;
        }
    }
#pragma unroll
    for (int c = 0; c < CPT; c++) {
        tsum[ty * COUT + c * 16 + tx] = vs[c];
        tsq[ty * COUT + c * 16 + tx] = vq[c];
    }
    __syncthreads();
    for (int col = threadIdx.x; col < COUT; col += 256) {
        float S = 0.f, Q = 0.f;
#pragma unroll 4
        for (int t = 0; t < 16; t++) { S += tsum[t * COUT + col]; Q += tsq[t * COUT + col]; }
        part[(size_t)blockIdx.x * 2 * COUT + col] = S;
        part[(size_t)blockIdx.x * 2 * COUT + COUT + col] = Q;
    }
}

// ---------------- aggregation post-GEMM (layer 1, C=64): bias+relu+stats, bf16 in/out ----------------

__global__ __launch_bounds__(256) void k_agg64(const unsigned short* __restrict__ H, const int* __restrict__ offs,
                                               const int2* __restrict__ csr, const float* __restrict__ dis,
                                               const float* __restrict__ bias, unsigned short* __restrict__ Y,
                                               float* __restrict__ part, int n) {
    const int lane = threadIdx.x & 63;
    const int wave = threadIdx.x >> 6;
    const int gw = blockIdx.x * 4 + wave;
    const int nw = gridDim.x * 4;
    float bsum = 0.f, bsq = 0.f;
    const float bias_r = bias[lane];

    for (int node = gw; node < n; node += nw) {
        int s0 = offs[node], s1 = offs[node + 1];
        float a = 0.f;
        int e = s0;
        for (; e + 2 <= s1; e += 2) {
            int2 e0 = csr[e], e1 = csr[e + 1];
            float v0 = __builtin_bit_cast(float, e0.y);
            float v1 = __builtin_bit_cast(float, e1.y);
            float h0 = bf2f(H[(size_t)e0.x * 64 + lane]);
            float h1 = bf2f(H[(size_t)e1.x * 64 + lane]);
            a += v0 * h0 + v1 * h1;
        }
        if (e < s1) {
            int2 e0 = csr[e];
            a += __builtin_bit_cast(float, e0.y) * bf2f(H[(size_t)e0.x * 64 + lane]);
        }
        float dn = dis[node];
        float val = a * dn + bf2f(H[(size_t)node * 64 + lane]) * dn * dn + bias_r;
        val = fmaxf(val, 0.f);
        Y[(size_t)node * 64 + lane] = f2bf(val);
        bsum += val;
        bsq += val * val;
    }
    __shared__ float psum[4][64], psq[4][64];
    psum[wave][lane] = bsum; psq[wave][lane] = bsq;
    __syncthreads();
    if (threadIdx.x < 64) {
        int c = threadIdx.x;
        float s = psum[0][c] + psum[1][c] + psum[2][c] + psum[3][c];
        float qq = psq[0][c] + psq[1][c] + psq[2][c] + psq[3][c];
        part[(size_t)blockIdx.x * 128 + c] = s;
        part[(size_t)blockIdx.x * 128 + 64 + c] = qq;
    }
}

// ---------------- aggregation pre-GEMM (layers 2,3): BN fold, bf16 in / fp32 out ----------------
// out[v][c] = dn * ( (A_c + dn*in[v][c])*sc_c + (S + dn)*sh_c )

template <int C>
__global__ __launch_bounds__(256) void k_aggpre(const unsigned short* __restrict__ IN, const int* __restrict__ offs,
                                                const int2* __restrict__ csr, const float* __restrict__ dis,
                                                const float* __restrict__ ss, float* __restrict__ OUT, int n) {
    constexpr int VPL = C / 64;
    const int lane = threadIdx.x & 63;
    const int wave = threadIdx.x >> 6;
    const int gw = blockIdx.x * 4 + wave;
    const int nw = gridDim.x * 4;
    float sc[VPL], sh[VPL];
#pragma unroll
    for (int q = 0; q < VPL; q++) { sc[q] = ss[lane * VPL + q]; sh[q] = ss[C + lane * VPL + q]; }

    for (int node = gw; node < n; node += nw) {
        int s0 = offs[node], s1 = offs[node + 1];
        float a[VPL];
        float S = 0.f;
#pragma unroll
        for (int q = 0; q < VPL; q++) a[q] = 0.f;
        int e = s0;
        for (; e + 2 <= s1; e += 2) {
            int2 e0 = csr[e], e1 = csr[e + 1];
            float v0 = __builtin_bit_cast(float, e0.y);
            float v1 = __builtin_bit_cast(float, e1.y);
            S += v0 + v1;
            if (VPL == 2) {
                unsigned int w0 = *(const unsigned int*)(IN + (size_t)e0.x * C + 2 * lane);
                unsigned int w1 = *(const unsigned int*)(IN + (size_t)e1.x * C + 2 * lane);
                a[0] += v0 * bflo(w0) + v1 * bflo(w1);
                a[1] += v0 * bfhi(w0) + v1 * bfhi(w1);
            } else {
                a[0] += v0 * bf2f(IN[(size_t)e0.x * C + lane]) + v1 * bf2f(IN[(size_t)e1.x * C + lane]);
            }
        }
        if (e < s1) {
            int2 e0 = csr[e];
            float v0 = __builtin_bit_cast(float, e0.y);
            S += v0;
            if (VPL == 2) {
                unsigned int w0 = *(const unsigned int*)(IN + (size_t)e0.x * C + 2 * lane);
                a[0] += v0 * bflo(w0);
                a[1] += v0 * bfhi(w0);
            } else {
                a[0] += v0 * bf2f(IN[(size_t)e0.x * C + lane]);
            }
        }
        float dn = dis[node];
        float shf = S + dn;
        if (VPL == 2) {
            unsigned int wsf = *(const unsigned int*)(IN + (size_t)node * C + 2 * lane);
            float o0 = dn * ((a[0] + dn * bflo(wsf)) * sc[0] + shf * sh[0]);
            float o1 = dn * ((a[1] + dn * bfhi(wsf)) * sc[1] + shf * sh[1]);
            *(float2*)(OUT + (size_t)node * C + 2 * lane) = make_float2(o0, o1);
        } else {
            float hsf = bf2f(IN[(size_t)node * C + lane]);
            OUT[(size_t)node * C + lane] = dn * ((a[0] + dn * hsf) * sc[0] + shf * sh[0]);
        }
    }
}

// ---------------- BN finalize ----------------

template <int C>
__global__ __launch_bounds__(1024) void k_bnfin(const float* __restrict__ part, int nblk,
                                                const float* __restrict__ g, const float* __restrict__ bt,
                                                float* __restrict__ ss, int n) {
    constexpr int ROWS = 1024 / C;
    __shared__ float ssum[1024], ssq[1024];
    const int c = threadIdx.x % C;
    const int r = threadIdx.x / C;
    float s = 0.f, q = 0.f;
    for (int b = r; b < nblk; b += ROWS) {
        s += part[(size_t)b * 2 * C + c];
        q += part[(size_t)b * 2 * C + C + c];
    }
    ssum[threadIdx.x] = s; ssq[threadIdx.x] = q;
    __syncthreads();
    if (r == 0) {
        double S = (double)s, Q = (double)q;
        for (int rr = 1; rr < ROWS; rr++) { S += (double)ssum[rr * C + c]; Q += (double)ssq[rr * C + c]; }
        double invN = 1.0 / (double)n;
        double mu = S * invN;
        double var = Q * invN - mu * mu;
        float scale = g[c] / sqrtf((float)var + 1e-5f);
        ss[c] = scale;
        ss[C + c] = bt[c] - (float)mu * scale;
    }
}

// ---------------- edge-pair scoring via MFMA (bf16 Z input) ----------------

__global__ __launch_bounds__(128) void k_score(const unsigned short* __restrict__ Z, const float* __restrict__ ss,
                                               const int* __restrict__ src, const int* __restrict__ dst,
                                               const unsigned short* __restrict__ Wt,
                                               const float* __restrict__ fcb1, const float* __restrict__ fcW2,
                                               const float* __restrict__ fcb2, float* __restrict__ out, int P) {
    __shared__ unsigned int emb[2][16][128];   // [wave][pair][u32 = 2 bf16] = 16KB
    const int lane = threadIdx.x & 63;
    const int wave = threadIdx.x >> 6;
    unsigned int (*Ew)[128] = emb[wave];
    const int tile = blockIdx.x * 2 + wave;
    const int pbase = tile * 16;

    const float2 sc2 = *(const float2*)&ss[2 * lane];
    const float2 sh2 = *(const float2*)&ss[128 + 2 * lane];

    // gather (bf16) + BN fold (fp32) + bf16 pack into swizzled LDS
#pragma unroll 4
    for (int p = 0; p < 16; ++p) {
        int pi = pbase + p;
        int is = src[pi], id = dst[pi];
        unsigned int wa = *(const unsigned int*)(Z + (size_t)is * 128 + 2 * lane);
        unsigned int wb = *(const unsigned int*)(Z + (size_t)id * 128 + 2 * lane);
        unsigned int ua = f2bf_pack(bflo(wa) * sc2.x + sh2.x, bfhi(wa) * sc2.y + sh2.y);
        unsigned int ub = f2bf_pack(bflo(wb) * sc2.x + sh2.x, bfhi(wb) * sc2.y + sh2.y);
        int swz = (p & 7) << 4;
        char* rowp = (char*)&Ew[p][0];
        *(unsigned int*)(rowp + ((lane * 4) ^ swz)) = ua;
        *(unsigned int*)(rowp + (((lane + 64) * 4) ^ swz)) = ub;
    }

    // A fragments: 8 K-steps
    const int m = lane & 15;
    const int g4 = lane >> 4;
    bf16x8 af[8];
    {
        const char* rowp = (const char*)&Ew[m][0];
        const int sw = (m & 7) << 4;
#pragma unroll
        for (int ks = 0; ks < 8; ++ks)
            af[ks] = *(const bf16x8*)(rowp + ((ks * 64 + g4 * 16) ^ sw));
    }

    float sacc[4] = {0.f, 0.f, 0.f, 0.f};
    const bf16x8* Wtv = (const bf16x8*)Wt;
#pragma unroll 2
    for (int nt = 0; nt < 8; ++nt) {
        f32x4 acc = {0.f, 0.f, 0.f, 0.f};
#pragma unroll
        for (int ks = 0; ks < 8; ++ks) {
            bf16x8 bf = Wtv[(nt * 8 + ks) * 64 + lane];
            acc = __builtin_amdgcn_mfma_f32_16x16x32_bf16(af[ks], bf, acc, 0, 0, 0);
        }
        int oc = nt * 16 + m;
        float b1 = fcb1[oc];
        float w2 = fcW2[oc];
#pragma unroll
        for (int r = 0; r < 4; ++r) {
            float h = fmaxf(acc[r] + b1, 0.f);
            sacc[r] += h * w2;
        }
    }

    const float b2v = fcb2[0];
#pragma unroll
    for (int r = 0; r < 4; ++r) {
        float s = sacc[r];
        s += __shfl_xor(s, 1);
        s += __shfl_xor(s, 2);
        s += __shfl_xor(s, 4);
        s += __shfl_xor(s, 8);
        if (m == 0) out[pbase + g4 * 4 + r] = s + b2v;
    }
}

// ---------------- launch ----------------

extern "C" void kernel_launch(void* const* d_in, const int* in_sizes, int n_in,
                              void* d_out, int out_size, void* d_ws, size_t ws_size,
                              hipStream_t stream) {
    const float* x   = (const float*)d_in[0];
    const int* ei    = (const int*)d_in[1];
    const int* src   = (const int*)d_in[2];
    const int* dst   = (const int*)d_in[3];
    const float* W1  = (const float*)d_in[4];
    const float* b1  = (const float*)d_in[5];
    const float* W2  = (const float*)d_in[6];
    const float* b2  = (const float*)d_in[7];
    const float* W3  = (const float*)d_in[8];
    const float* b3  = (const float*)d_in[9];
    const float* g1  = (const float*)d_in[10];
    const float* bt1 = (const float*)d_in[11];
    const float* g2  = (const float*)d_in[12];
    const float* bt2 = (const float*)d_in[13];
    const float* g3  = (const float*)d_in[14];
    const float* bt3 = (const float*)d_in[15];
    const float* fcW1 = (const float*)d_in[16];
    const float* fcb1 = (const float*)d_in[17];
    const float* fcW2 = (const float*)d_in[18];
    const float* fcb2 = (const float*)d_in[19];
    float* out = (float*)d_out;

    const int N = in_sizes[0] / 128;   // 50000
    const int E = in_sizes[1] / 2;     // 1600000
    const int P = in_sizes[2];         // 200000
    const int* erow = ei;
    const int* ecol = ei + E;

    const int AGG_GRID = 2048;

    char* w = (char*)d_ws;
    auto alloc = [&](size_t bytes) { void* p = (void*)w; w += (bytes + 255) & ~(size_t)255; return p; };
    int*   deg     = (int*)alloc((size_t)N * 4);
    float* dis     = (float*)alloc((size_t)N * 4);
    int*   offs    = (int*)alloc((size_t)(N + 1) * 4);
    int*   cursor  = (int*)alloc((size_t)N * 4);
    int*   bsum    = (int*)alloc((size_t)64 * 4);
    int2*  csr     = (int2*)alloc((size_t)E * 8);
    float* part    = (float*)alloc((size_t)AGG_GRID * 256 * 4);
    float* ss1     = (float*)alloc(2 * 64 * 4);
    float* ss2     = (float*)alloc(2 * 128 * 4);
    float* ss3     = (float*)alloc(2 * 128 * 4);
    unsigned short* Wt  = (unsigned short*)alloc((size_t)4096 * 8 * 2);
    unsigned short* bhA = (unsigned short*)alloc((size_t)N * 128 * 2);
    unsigned short* bhB = (unsigned short*)alloc((size_t)N * 128 * 2);
    float* bufF    = (float*)alloc((size_t)N * 128 * 4);
    (void)ws_size; (void)n_in; (void)out_size;

    const int nb_n = (N + 255) / 256;
    const int nb_e = (E + 255) / 256;
    const int nb_s = (N + 1023) / 1024;

    // CSR build + W1 tile prep
    k_init_deg<<<nb_n, 256, 0, stream>>>(deg, N);
    k_count<<<nb_e, 256, 0, stream>>>(ecol, deg, E);
    k_dis<<<nb_n, 256, 0, stream>>>(deg, dis, N);
    k_scan_blk<<<nb_s, 1024, 0, stream>>>(deg, offs, bsum, N);
    k_scan_top<<<1, 64, 0, stream>>>(bsum, nb_s);
    k_scan_add<<<nb_s, 1024, 0, stream>>>(offs, cursor, bsum, N, nb_s);
    k_fill<<<nb_e, 256, 0, stream>>>(erow, ecol, dis, cursor, csr, E);
    k_prepw<<<16, 256, 0, stream>>>(fcW1, Wt);

    const int gemm_grid = (N + 63) / 64;

    // layer 1: gemm(x @ W1) -> bf16 -> agg(+bias,relu,stats) -> bf16
    k_gemm<128, 64><<<gemm_grid, 256, 0, stream>>>(x, W1, bhA, N);
    k_agg64<<<AGG_GRID, 256, 0, stream>>>(bhA, offs, csr, dis, b1, bhB, part, N);
    k_bnfin<64><<<1, 1024, 0, stream>>>(part, AGG_GRID, g1, bt1, ss1, N);

    // layer 2: aggpre(BN1-fold, 64ch bf16) -> fp32 -> gemmf(W2 +bias,relu,stats) -> bf16
    k_aggpre<64><<<AGG_GRID, 256, 0, stream>>>(bhB, offs, csr, dis, ss1, bufF, N);
    k_gemmf<64, 128><<<gemm_grid, 256, 0, stream>>>(bufF, W2, b2, bhA, part, N);
    k_bnfin<128><<<1, 1024, 0, stream>>>(part, gemm_grid, g2, bt2, ss2, N);

    // layer 3: aggpre(BN2-fold, 128ch bf16) -> fp32 -> gemmf(W3 +bias,relu,stats) -> bf16
    k_aggpre<128><<<AGG_GRID, 256, 0, stream>>>(bhA, offs, csr, dis, ss2, bufF, N);
    k_gemmf<128, 128><<<gemm_grid, 256, 0, stream>>>(bufF, W3, b3, bhB, part, N);
    k_bnfin<128><<<1, 1024, 0, stream>>>(part, gemm_grid, g3, bt3, ss3, N);

    // edge-pair scoring (MFMA): 32 pairs per 128-thread block
    const int score_grid = P / 32;
    k_score<<<score_grid, 128, 0, stream>>>(bhB, ss3, src, dst, Wt, fcb1, fcW2, fcb2, out, P);
}

// Round 6
// 695.596 us; speedup vs baseline: 3.5011x; 1.1280x over previous
//
#include <hip/hip_runtime.h>
#include <math.h>

typedef short bf16x8 __attribute__((ext_vector_type(8)));
typedef float f32x4 __attribute__((ext_vector_type(4)));

__device__ inline unsigned int f2bf_pack(float lo, float hi) {
    unsigned int ul = __builtin_bit_cast(unsigned int, lo);
    unsigned int uh = __builtin_bit_cast(unsigned int, hi);
    ul = ul + 0x7fffu + ((ul >> 16) & 1u);
    uh = uh + 0x7fffu + ((uh >> 16) & 1u);
    return (ul >> 16) | (uh & 0xffff0000u);
}
__device__ inline unsigned short f2bf(float f) {
    unsigned int u = __builtin_bit_cast(unsigned int, f);
    u = u + 0x7fffu + ((u >> 16) & 1u);
    return (unsigned short)(u >> 16);
}
__device__ inline float bf2f(unsigned short u) {
    return __builtin_bit_cast(float, (unsigned int)u << 16);
}
__device__ inline float bflo(unsigned int w) { return __builtin_bit_cast(float, w << 16); }
__device__ inline float bfhi(unsigned int w) { return __builtin_bit_cast(float, w & 0xffff0000u); }

// ---------------- degree / scan ----------------

__global__ __launch_bounds__(256) void k_init_deg(int* deg, int n) {
    int i = blockIdx.x * 256 + threadIdx.x;
    if (i < n) deg[i] = 1;  // self-loop
}

__global__ __launch_bounds__(256) void k_count(const int* __restrict__ col, int* deg, int E) {
    int e = blockIdx.x * 256 + threadIdx.x;
    if (e < E) atomicAdd(&deg[col[e]], 1);
}

__global__ __launch_bounds__(256) void k_dis(const int* __restrict__ deg, float* __restrict__ dis, int n) {
    int i = blockIdx.x * 256 + threadIdx.x;
    if (i < n) dis[i] = 1.0f / sqrtf((float)deg[i]);
}

__global__ __launch_bounds__(1024) void k_scan_blk(const int* __restrict__ deg,
                                                   int* __restrict__ offs, int* __restrict__ bsum, int n) {
    __shared__ int tmp[1024];
    int i = blockIdx.x * 1024 + threadIdx.x;
    int v = (i < n) ? (deg[i] - 1) : 0;
    tmp[threadIdx.x] = v;
    __syncthreads();
    for (int off = 1; off < 1024; off <<= 1) {
        int t = (threadIdx.x >= off) ? tmp[threadIdx.x - off] : 0;
        __syncthreads();
        tmp[threadIdx.x] += t;
        __syncthreads();
    }
    if (i < n) offs[i] = tmp[threadIdx.x] - v;
    if (threadIdx.x == 1023) bsum[blockIdx.x] = tmp[1023];
}

__global__ void k_scan_top(int* bsum, int nb) {
    if (threadIdx.x == 0) {
        int acc = 0;
        for (int b = 0; b < nb; b++) { int t = bsum[b]; bsum[b] = acc; acc += t; }
        bsum[nb] = acc;
    }
}

__global__ __launch_bounds__(1024) void k_scan_add(int* __restrict__ offs, int* __restrict__ cursor,
                                                   const int* __restrict__ bsum, int n, int nb) {
    int i = blockIdx.x * 1024 + threadIdx.x;
    if (i < n) {
        int v = offs[i] + bsum[blockIdx.x];
        offs[i] = v;
        cursor[i] = v;
    }
    if (i == 0) offs[n] = bsum[nb];
}

// ---------------- binned CSR build (replaces random scatter k_fill) ----------------
// bucket = dst >> 9 (512 nodes/bucket, <=128 buckets). Pass A: LDS-staged binning with
// contiguous 8B-entry flushes via atomic bucket cursors (bucket base = offs[b<<9]).
// Pass B: per-bucket exact-position scatter; write window ~135KB -> L2-coalesced writeback.

__global__ void k_bcur(const int* __restrict__ offs, int* __restrict__ bcur, int NB) {
    int b = threadIdx.x;
    if (b < NB) bcur[b] = offs[b << 9];
}

__global__ __launch_bounds__(256) void k_binA(const int* __restrict__ row, const int* __restrict__ col,
                                              int* __restrict__ bcur, int2* __restrict__ binned,
                                              int E, int NB) {
    constexpr int SLOTS = 32;
    constexpr int CHUNK = 2048;
    __shared__ int2 stage[128][SLOTS];
    __shared__ int lcount[128];
    for (int b = threadIdx.x; b < 128; b += 256) lcount[b] = 0;
    __syncthreads();
    for (int cs = blockIdx.x * CHUNK; cs < E; cs += gridDim.x * CHUNK) {
        // append
#pragma unroll
        for (int j = 0; j < CHUNK / 256; ++j) {
            int e = cs + j * 256 + threadIdx.x;
            if (e < E) {
                int r = row[e], c = col[e];
                int b = c >> 9;
                int pos = atomicAdd(&lcount[b], 1);
                if (pos < SLOTS) stage[b][pos] = make_int2(r, c);
                else {
                    int gp = atomicAdd(&bcur[b], 1);   // rare overflow fallback
                    binned[gp] = make_int2(r, c);
                }
            }
        }
        __syncthreads();
        // flush contiguous runs
        for (int b = threadIdx.x; b < NB; b += 256) {
            int c = lcount[b];
            if (c > SLOTS) c = SLOTS;
            if (c > 0) {
                int gp = atomicAdd(&bcur[b], c);
                for (int j = 0; j < c; ++j) binned[gp + j] = stage[b][j];
            }
            lcount[b] = 0;
        }
        __syncthreads();
    }
}

__global__ __launch_bounds__(256) void k_binB(const int2* __restrict__ binned, const int* __restrict__ offs,
                                              const float* __restrict__ dis, int* __restrict__ cursor,
                                              int2* __restrict__ csr, int N, int NB) {
    int b = blockIdx.x >> 2;
    int s = blockIdx.x & 3;
    int n1 = (b + 1) << 9; if (n1 > N) n1 = N;
    int lo = offs[b << 9];
    int hi = offs[n1];
    int cnt = hi - lo;
    int q0 = lo + (int)(((long long)cnt * s) >> 2);
    int q1 = lo + (int)(((long long)cnt * (s + 1)) >> 2);
    for (int i = q0 + threadIdx.x; i < q1; i += 256) {
        int2 e = binned[i];
        int pos = atomicAdd(&cursor[e.y], 1);
        csr[pos] = make_int2(e.x, __builtin_bit_cast(int, dis[e.x]));
    }
}

// ---------------- fp32 -> bf16 cast (x input) ----------------

__global__ __launch_bounds__(256) void k_cast(const float* __restrict__ X, unsigned short* __restrict__ Y, int n8) {
    int i = blockIdx.x * 256 + threadIdx.x;
    if (i >= n8) return;
    const float4* x4 = (const float4*)X;
    float4 a = x4[2 * i], b = x4[2 * i + 1];
    uint4 o = make_uint4(f2bf_pack(a.x, a.y), f2bf_pack(a.z, a.w),
                         f2bf_pack(b.x, b.y), f2bf_pack(b.z, b.w));
    *(uint4*)(Y + (size_t)i * 8) = o;
}

// ---------------- W[K x COUT] fp32 -> bf16 MFMA B-fragment tiles ----------------
// group g=(nt*(K/32)+ks)*64+l holds 8 bf16: B[k=ks*32+(l>>4)*8+j][n=nt*16+(l&15)]

template <int K, int COUT>
__global__ __launch_bounds__(256) void k_prep(const float* __restrict__ W, unsigned short* __restrict__ Wt) {
    constexpr int NG = (COUT / 16) * (K / 32) * 64;
    int g = blockIdx.x * 256 + threadIdx.x;
    if (g >= NG) return;
    int l = g & 63;
    int ks = (g >> 6) % (K / 32);
    int nt = g / (64 * (K / 32));
    int n = nt * 16 + (l & 15);
    int k0 = ks * 32 + (l >> 4) * 8;
    unsigned int w[4];
#pragma unroll
    for (int j = 0; j < 4; ++j) {
        float a = W[(size_t)(k0 + 2 * j) * COUT + n];
        float b = W[(size_t)(k0 + 2 * j + 1) * COUT + n];
        w[j] = f2bf_pack(a, b);
    }
    *(uint4*)(Wt + (size_t)g * 8) = make_uint4(w[0], w[1], w[2], w[3]);
}

// ---------------- MFMA GEMM: H = X(bf16) @ W (+bias,relu,stats if FUSED), bf16 out ----------------
// 4 waves/block, 64 rows/block. A-frags loaded DIRECTLY from global (16 rows x 16B at
// same column block = 16 full 64B lines per load inst -> no LDS staging/barriers).
// Layout = k_score's verified convention: A lane m=l&15,k0=(l>>4)*8; C col=l&15, row=(l>>4)*4+r.

template <int K, int COUT, bool FUSED>
__global__ __launch_bounds__(256) void k_mgemm(const unsigned short* __restrict__ Xb,
                                               const unsigned short* __restrict__ Wt,
                                               const float* __restrict__ bias,
                                               unsigned short* __restrict__ H,
                                               float* __restrict__ part, int n) {
    constexpr int NT = COUT / 16;
    constexpr int KS = K / 32;
    __shared__ float reds[FUSED ? 16 : 1][COUT];
    __shared__ float redq[FUSED ? 16 : 1][COUT];
    const int lane = threadIdx.x & 63;
    const int wave = threadIdx.x >> 6;
    const int m = lane & 15, g4 = lane >> 4;
    const int rb = blockIdx.x * 64 + wave * 16;

    bf16x8 af[KS];
    {
        int arow = rb + m;
        if (arow >= n) arow = n - 1;   // clamp; stores guarded
        const unsigned short* xr = Xb + (size_t)arow * K + g4 * 8;
#pragma unroll
        for (int ks = 0; ks < KS; ++ks) af[ks] = *(const bf16x8*)(xr + ks * 32);
    }
    const bf16x8* Wv = (const bf16x8*)Wt;
    f32x4 acc[NT];
#pragma unroll
    for (int nt = 0; nt < NT; ++nt) {
        f32x4 a = {0.f, 0.f, 0.f, 0.f};
#pragma unroll
        for (int ks = 0; ks < KS; ++ks)
            a = __builtin_amdgcn_mfma_f32_16x16x32_bf16(af[ks], Wv[(nt * KS + ks) * 64 + lane], a, 0, 0, 0);
        acc[nt] = a;
    }

    if (!FUSED) {
#pragma unroll
        for (int nt = 0; nt < NT; ++nt)
#pragma unroll
            for (int r = 0; r < 4; ++r) {
                int gr = rb + g4 * 4 + r;
                if (gr < n) H[(size_t)gr * COUT + nt * 16 + m] = f2bf(acc[nt][r]);
            }
    } else {
        float vs[NT], vq[NT];
#pragma unroll
        for (int nt = 0; nt < NT; ++nt) {
            float b1 = bias[nt * 16 + m];
            vs[nt] = 0.f; vq[nt] = 0.f;
#pragma unroll
            for (int r = 0; r < 4; ++r) {
                int gr = rb + g4 * 4 + r;
                bool ok = gr < n;
                float val = ok ? fmaxf(acc[nt][r] + b1, 0.f) : 0.f;
                if (ok) H[(size_t)gr * COUT + nt * 16 + m] = f2bf(val);
                vs[nt] += val;
                vq[nt] += val * val;
            }
        }
#pragma unroll
        for (int nt = 0; nt < NT; ++nt) {
            reds[wave * 4 + g4][nt * 16 + m] = vs[nt];
            redq[wave * 4 + g4][nt * 16 + m] = vq[nt];
        }
        __syncthreads();
        for (int c = threadIdx.x; c < COUT; c += 256) {
            float S = 0.f, Q = 0.f;
#pragma unroll
            for (int t = 0; t < 16; ++t) { S += reds[t][c]; Q += redq[t][c]; }
            part[(size_t)blockIdx.x * 2 * COUT + c] = S;
            part[(size_t)blockIdx.x * 2 * COUT + COUT + c] = Q;
        }
    }
}

// ---------------- aggregation post-GEMM (layer 1, C=64): bias+relu+stats, bf16 in/out ----------------

__global__ __launch_bounds__(256) void k_agg64(const unsigned short* __restrict__ H, const int* __restrict__ offs,
                                               const int2* __restrict__ csr, const float* __restrict__ dis,
                                               const float* __restrict__ bias, unsigned short* __restrict__ Y,
                                               float* __restrict__ part, int n) {
    const int lane = threadIdx.x & 63;
    const int wave = threadIdx.x >> 6;
    const int gw = blockIdx.x * 4 + wave;
    const int nw = gridDim.x * 4;
    float bsum = 0.f, bsq = 0.f;
    const float bias_r = bias[lane];

    for (int node = gw; node < n; node += nw) {
        int s0 = offs[node], s1 = offs[node + 1];
        float a = 0.f;
        int e = s0;
        for (; e + 2 <= s1; e += 2) {
            int2 e0 = csr[e], e1 = csr[e + 1];
            float v0 = __builtin_bit_cast(float, e0.y);
            float v1 = __builtin_bit_cast(float, e1.y);
            float h0 = bf2f(H[(size_t)e0.x * 64 + lane]);
            float h1 = bf2f(H[(size_t)e1.x * 64 + lane]);
            a += v0 * h0 + v1 * h1;
        }
        if (e < s1) {
            int2 e0 = csr[e];
            a += __builtin_bit_cast(float, e0.y) * bf2f(H[(size_t)e0.x * 64 + lane]);
        }
        float dn = dis[node];
        float val = a * dn + bf2f(H[(size_t)node * 64 + lane]) * dn * dn + bias_r;
        val = fmaxf(val, 0.f);
        Y[(size_t)node * 64 + lane] = f2bf(val);
        bsum += val;
        bsq += val * val;
    }
    __shared__ float psum[4][64], psq[4][64];
    psum[wave][lane] = bsum; psq[wave][lane] = bsq;
    __syncthreads();
    if (threadIdx.x < 64) {
        int c = threadIdx.x;
        float s = psum[0][c] + psum[1][c] + psum[2][c] + psum[3][c];
        float qq = psq[0][c] + psq[1][c] + psq[2][c] + psq[3][c];
        part[(size_t)blockIdx.x * 128 + c] = s;
        part[(size_t)blockIdx.x * 128 + 64 + c] = qq;
    }
}

// ---------------- aggregation pre-GEMM (layers 2,3): BN fold, bf16 in / bf16 out ----------------
// out[v][c] = dn * ( (A_c + dn*in[v][c])*sc_c + (S + dn)*sh_c )

template <int C>
__global__ __launch_bounds__(256) void k_aggpre(const unsigned short* __restrict__ IN, const int* __restrict__ offs,
                                                const int2* __restrict__ csr, const float* __restrict__ dis,
                                                const float* __restrict__ ss, unsigned short* __restrict__ OUT, int n) {
    constexpr int VPL = C / 64;
    const int lane = threadIdx.x & 63;
    const int wave = threadIdx.x >> 6;
    const int gw = blockIdx.x * 4 + wave;
    const int nw = gridDim.x * 4;
    float sc[VPL], sh[VPL];
#pragma unroll
    for (int q = 0; q < VPL; q++) { sc[q] = ss[lane * VPL + q]; sh[q] = ss[C + lane * VPL + q]; }

    for (int node = gw; node < n; node += nw) {
        int s0 = offs[node], s1 = offs[node + 1];
        float a[VPL];
        float S = 0.f;
#pragma unroll
        for (int q = 0; q < VPL; q++) a[q] = 0.f;
        int e = s0;
        for (; e + 2 <= s1; e += 2) {
            int2 e0 = csr[e], e1 = csr[e + 1];
            float v0 = __builtin_bit_cast(float, e0.y);
            float v1 = __builtin_bit_cast(float, e1.y);
            S += v0 + v1;
            if (VPL == 2) {
                unsigned int w0 = *(const unsigned int*)(IN + (size_t)e0.x * C + 2 * lane);
                unsigned int w1 = *(const unsigned int*)(IN + (size_t)e1.x * C + 2 * lane);
                a[0] += v0 * bflo(w0) + v1 * bflo(w1);
                a[1] += v0 * bfhi(w0) + v1 * bfhi(w1);
            } else {
                a[0] += v0 * bf2f(IN[(size_t)e0.x * C + lane]) + v1 * bf2f(IN[(size_t)e1.x * C + lane]);
            }
        }
        if (e < s1) {
            int2 e0 = csr[e];
            float v0 = __builtin_bit_cast(float, e0.y);
            S += v0;
            if (VPL == 2) {
                unsigned int w0 = *(const unsigned int*)(IN + (size_t)e0.x * C + 2 * lane);
                a[0] += v0 * bflo(w0);
                a[1] += v0 * bfhi(w0);
            } else {
                a[0] += v0 * bf2f(IN[(size_t)e0.x * C + lane]);
            }
        }
        float dn = dis[node];
        float shf = S + dn;
        if (VPL == 2) {
            unsigned int wsf = *(const unsigned int*)(IN + (size_t)node * C + 2 * lane);
            float o0 = dn * ((a[0] + dn * bflo(wsf)) * sc[0] + shf * sh[0]);
            float o1 = dn * ((a[1] + dn * bfhi(wsf)) * sc[1] + shf * sh[1]);
            *(unsigned int*)(OUT + (size_t)node * C + 2 * lane) = f2bf_pack(o0, o1);
        } else {
            float hsf = bf2f(IN[(size_t)node * C + lane]);
            OUT[(size_t)node * C + lane] = f2bf(dn * ((a[0] + dn * hsf) * sc[0] + shf * sh[0]));
        }
    }
}

// ---------------- BN finalize ----------------

template <int C>
__global__ __launch_bounds__(1024) void k_bnfin(const float* __restrict__ part, int nblk,
                                                const float* __restrict__ g, const float* __restrict__ bt,
                                                float* __restrict__ ss, int n) {
    constexpr int ROWS = 1024 / C;
    __shared__ float ssum[1024], ssq[1024];
    const int c = threadIdx.x % C;
    const int r = threadIdx.x / C;
    float s = 0.f, q = 0.f;
    for (int b = r; b < nblk; b += ROWS) {
        s += part[(size_t)b * 2 * C + c];
        q += part[(size_t)b * 2 * C + C + c];
    }
    ssum[threadIdx.x] = s; ssq[threadIdx.x] = q;
    __syncthreads();
    if (r == 0) {
        double S = (double)s, Q = (double)q;
        for (int rr = 1; rr < ROWS; rr++) { S += (double)ssum[rr * C + c]; Q += (double)ssq[rr * C + c]; }
        double invN = 1.0 / (double)n;
        double mu = S * invN;
        double var = Q * invN - mu * mu;
        float scale = g[c] / sqrtf((float)var + 1e-5f);
        ss[c] = scale;
        ss[C + c] = bt[c] - (float)mu * scale;
    }
}

// ---------------- edge-pair scoring via MFMA (bf16 Z input) ----------------

__global__ __launch_bounds__(128) void k_score(const unsigned short* __restrict__ Z, const float* __restrict__ ss,
                                               const int* __restrict__ src, const int* __restrict__ dst,
                                               const unsigned short* __restrict__ Wt,
                                               const float* __restrict__ fcb1, const float* __restrict__ fcW2,
                                               const float* __restrict__ fcb2, float* __restrict__ out, int P) {
    __shared__ unsigned int emb[2][16][128];   // [wave][pair][u32 = 2 bf16] = 16KB
    const int lane = threadIdx.x & 63;
    const int wave = threadIdx.x >> 6;
    unsigned int (*Ew)[128] = emb[wave];
    const int tile = blockIdx.x * 2 + wave;
    const int pbase = tile * 16;

    const float2 sc2 = *(const float2*)&ss[2 * lane];
    const float2 sh2 = *(const float2*)&ss[128 + 2 * lane];

#pragma unroll 4
    for (int p = 0; p < 16; ++p) {
        int pi = pbase + p;
        int is = src[pi], id = dst[pi];
        unsigned int wa = *(const unsigned int*)(Z + (size_t)is * 128 + 2 * lane);
        unsigned int wb = *(const unsigned int*)(Z + (size_t)id * 128 + 2 * lane);
        unsigned int ua = f2bf_pack(bflo(wa) * sc2.x + sh2.x, bfhi(wa) * sc2.y + sh2.y);
        unsigned int ub = f2bf_pack(bflo(wb) * sc2.x + sh2.x, bfhi(wb) * sc2.y + sh2.y);
        int swz = (p & 7) << 4;
        char* rowp = (char*)&Ew[p][0];
        *(unsigned int*)(rowp + ((lane * 4) ^ swz)) = ua;
        *(unsigned int*)(rowp + (((lane + 64) * 4) ^ swz)) = ub;
    }

    const int m = lane & 15;
    const int g4 = lane >> 4;
    bf16x8 af[8];
    {
        const char* rowp = (const char*)&Ew[m][0];
        const int sw = (m & 7) << 4;
#pragma unroll
        for (int ks = 0; ks < 8; ++ks)
            af[ks] = *(const bf16x8*)(rowp + ((ks * 64 + g4 * 16) ^ sw));
    }

    float sacc[4] = {0.f, 0.f, 0.f, 0.f};
    const bf16x8* Wtv = (const bf16x8*)Wt;
#pragma unroll 2
    for (int nt = 0; nt < 8; ++nt) {
        f32x4 acc = {0.f, 0.f, 0.f, 0.f};
#pragma unroll
        for (int ks = 0; ks < 8; ++ks) {
            bf16x8 bf = Wtv[(nt * 8 + ks) * 64 + lane];
            acc = __builtin_amdgcn_mfma_f32_16x16x32_bf16(af[ks], bf, acc, 0, 0, 0);
        }
        int oc = nt * 16 + m;
        float b1 = fcb1[oc];
        float w2 = fcW2[oc];
#pragma unroll
        for (int r = 0; r < 4; ++r) {
            float h = fmaxf(acc[r] + b1, 0.f);
            sacc[r] += h * w2;
        }
    }

    const float b2v = fcb2[0];
#pragma unroll
    for (int r = 0; r < 4; ++r) {
        float s = sacc[r];
        s += __shfl_xor(s, 1);
        s += __shfl_xor(s, 2);
        s += __shfl_xor(s, 4);
        s += __shfl_xor(s, 8);
        if (m == 0) out[pbase + g4 * 4 + r] = s + b2v;
    }
}

// ---------------- launch ----------------

extern "C" void kernel_launch(void* const* d_in, const int* in_sizes, int n_in,
                              void* d_out, int out_size, void* d_ws, size_t ws_size,
                              hipStream_t stream) {
    const float* x   = (const float*)d_in[0];
    const int* ei    = (const int*)d_in[1];
    const int* src   = (const int*)d_in[2];
    const int* dst   = (const int*)d_in[3];
    const float* W1  = (const float*)d_in[4];
    const float* b1  = (const float*)d_in[5];
    const float* W2  = (const float*)d_in[6];
    const float* b2  = (const float*)d_in[7];
    const float* W3  = (const float*)d_in[8];
    const float* b3  = (const float*)d_in[9];
    const float* g1  = (const float*)d_in[10];
    const float* bt1 = (const float*)d_in[11];
    const float* g2  = (const float*)d_in[12];
    const float* bt2 = (const float*)d_in[13];
    const float* g3  = (const float*)d_in[14];
    const float* bt3 = (const float*)d_in[15];
    const float* fcW1 = (const float*)d_in[16];
    const float* fcb1 = (const float*)d_in[17];
    const float* fcW2 = (const float*)d_in[18];
    const float* fcb2 = (const float*)d_in[19];
    float* out = (float*)d_out;

    const int N = in_sizes[0] / 128;   // 50000
    const int E = in_sizes[1] / 2;     // 1600000
    const int P = in_sizes[2];         // 200000
    const int* erow = ei;
    const int* ecol = ei + E;
    const int NB = (N + 511) >> 9;     // 98 buckets

    const int AGG_GRID = 2048;

    char* w = (char*)d_ws;
    auto alloc = [&](size_t bytes) { void* p = (void*)w; w += (bytes + 255) & ~(size_t)255; return p; };
    int*   deg     = (int*)alloc((size_t)N * 4);
    float* dis     = (float*)alloc((size_t)N * 4);
    int*   offs    = (int*)alloc((size_t)(N + 1) * 4);
    int*   cursor  = (int*)alloc((size_t)N * 4);
    int*   bsum    = (int*)alloc((size_t)64 * 4);
    int*   bcur    = (int*)alloc((size_t)128 * 4);
    int2*  csr     = (int2*)alloc((size_t)E * 8);
    int2*  binned  = (int2*)alloc((size_t)E * 8);
    float* part    = (float*)alloc((size_t)AGG_GRID * 256 * 4);
    float* ss1     = (float*)alloc(2 * 64 * 4);
    float* ss2     = (float*)alloc(2 * 128 * 4);
    float* ss3     = (float*)alloc(2 * 128 * 4);
    unsigned short* Wts = (unsigned short*)alloc((size_t)4096 * 8 * 2);   // scoring W1 (256x128)
    unsigned short* Wt1 = (unsigned short*)alloc((size_t)1024 * 8 * 2);   // conv W1 (128x64)
    unsigned short* Wt2 = (unsigned short*)alloc((size_t)1024 * 8 * 2);   // conv W2 (64x128)
    unsigned short* Wt3 = (unsigned short*)alloc((size_t)2048 * 8 * 2);   // conv W3 (128x128)
    unsigned short* Xb1 = (unsigned short*)alloc((size_t)N * 128 * 2);
    unsigned short* bhA = (unsigned short*)alloc((size_t)N * 128 * 2);
    unsigned short* bhB = (unsigned short*)alloc((size_t)N * 128 * 2);
    (void)ws_size; (void)n_in; (void)out_size;

    const int nb_n = (N + 255) / 256;
    const int nb_e = (E + 255) / 256;
    const int nb_s = (N + 1023) / 1024;

    // degree + scan + binned CSR build
    k_init_deg<<<nb_n, 256, 0, stream>>>(deg, N);
    k_count<<<nb_e, 256, 0, stream>>>(ecol, deg, E);
    k_dis<<<nb_n, 256, 0, stream>>>(deg, dis, N);
    k_scan_blk<<<nb_s, 1024, 0, stream>>>(deg, offs, bsum, N);
    k_scan_top<<<1, 64, 0, stream>>>(bsum, nb_s);
    k_scan_add<<<nb_s, 1024, 0, stream>>>(offs, cursor, bsum, N, nb_s);
    k_bcur<<<1, 256, 0, stream>>>(offs, bcur, NB);
    k_binA<<<256, 256, 0, stream>>>(erow, ecol, bcur, binned, E, NB);
    k_binB<<<NB * 4, 256, 0, stream>>>(binned, offs, dis, cursor, csr, N, NB);

    // weight prep + input cast
    k_prep<256, 128><<<16, 256, 0, stream>>>(fcW1, Wts);
    k_prep<128, 64><<<4, 256, 0, stream>>>(W1, Wt1);
    k_prep<64, 128><<<4, 256, 0, stream>>>(W2, Wt2);
    k_prep<128, 128><<<8, 256, 0, stream>>>(W3, Wt3);
    k_cast<<<(N * 16 + 255) / 256, 256, 0, stream>>>(x, Xb1, N * 16);

    const int gemm_grid = (N + 63) / 64;

    // layer 1: mgemm(x @ W1) -> agg(+bias,relu,stats)
    k_mgemm<128, 64, false><<<gemm_grid, 256, 0, stream>>>(Xb1, Wt1, nullptr, bhA, nullptr, N);
    k_agg64<<<AGG_GRID, 256, 0, stream>>>(bhA, offs, csr, dis, b1, bhB, part, N);
    k_bnfin<64><<<1, 1024, 0, stream>>>(part, AGG_GRID, g1, bt1, ss1, N);

    // layer 2: aggpre(BN1-fold, 64ch) -> mgemm(W2 +bias,relu,stats)
    k_aggpre<64><<<AGG_GRID, 256, 0, stream>>>(bhB, offs, csr, dis, ss1, Xb1, N);
    k_mgemm<64, 128, true><<<gemm_grid, 256, 0, stream>>>(Xb1, Wt2, b2, bhA, part, N);
    k_bnfin<128><<<1, 1024, 0, stream>>>(part, gemm_grid, g2, bt2, ss2, N);

    // layer 3: aggpre(BN2-fold, 128ch) -> mgemm(W3 +bias,relu,stats)
    k_aggpre<128><<<AGG_GRID, 256, 0, stream>>>(bhA, offs, csr, dis, ss2, Xb1, N);
    k_mgemm<128, 128, true><<<gemm_grid, 256, 0, stream>>>(Xb1, Wt3, b3, bhB, part, N);
    k_bnfin<128><<<1, 1024, 0, stream>>>(part, gemm_grid, g3, bt3, ss3, N);

    // edge-pair scoring (MFMA): 32 pairs per 128-thread block
    const int score_grid = P / 32;
    k_score<<<score_grid, 128, 0, stream>>>(bhB, ss3, src, dst, Wts, fcb1, fcW2, fcb2, out, P);
}